// Round 5
// baseline (123.104 us; speedup 1.0000x reference)
//
#include <hip/hip_runtime.h>
#include <hip/hip_bf16.h>
#include <math.h>

#define S_LEN 4096

typedef unsigned short u16t;
typedef unsigned int u32t;
typedef __attribute__((ext_vector_type(4))) short bf16x4;
typedef __attribute__((ext_vector_type(8))) short bf16x8;
typedef __attribute__((ext_vector_type(4))) float f32x4;

__device__ __forceinline__ u16t f2bf_u16(float f) {
  union { __hip_bfloat16 h; u16t u; } r; r.h = __float2bfloat16(f); return r.u;
}

// async global->LDS, 16B per lane; LDS dest = wave-uniform base + lane*16
__device__ __forceinline__ void stage16(const u16t* g, u16t* l) {
  __builtin_amdgcn_global_load_lds(
      (const __attribute__((address_space(1))) void*)g,
      (__attribute__((address_space(3))) void*)l, 16, 0, 0);
}

// fragment load as two ds_read_b64 (rows may be only 8B-aligned)
__device__ __forceinline__ bf16x8 ld_frag(const u16t* p) {
  bf16x4 a = *(const bf16x4*)p;
  bf16x4 b = *(const bf16x4*)(p + 4);
  return __builtin_shufflevector(a, b, 0, 1, 2, 3, 4, 5, 6, 7);
}

// ---------------- RoPE table, layout [32 freq][4096 s] ----------------
__global__ __launch_bounds__(256) void rope_table_kernel(
    const int* __restrict__ pos, float* __restrict__ cosT, float* __restrict__ sinT)
{
  int idx = blockIdx.x * 256 + threadIdx.x;
  if (idx >= 32 * S_LEN) return;
  int j = idx >> 12, s = idx & 4095;
  double p = (double)pos[s];
  double inv = exp(-((double)(2 * j) / 64.0) * log(10000.0));
  double a = p * inv;
  cosT[idx] = (float)cos(a);
  sinT[idx] = (float)sin(a);
}

// ---------------- flat f32 -> bf16 cast (n4 float4's) ----------------
__global__ __launch_bounds__(256) void castw_kernel(
    const float* __restrict__ src, u16t* __restrict__ dst, int n4)
{
  int i = blockIdx.x * 256 + threadIdx.x;
  if (i >= n4) return;
  float4 v = ((const float4*)src)[i];
  union { u16t h[4]; uint2 u; } r;
  r.h[0] = f2bf_u16(v.x); r.h[1] = f2bf_u16(v.y);
  r.h[2] = f2bf_u16(v.z); r.h[3] = f2bf_u16(v.w);
  ((uint2*)dst)[i] = r.u;
}

// ---------------- x [768][4096] f32 -> xT [4096][768] bf16 ----------------
__global__ __launch_bounds__(256) void tcast_kernel(
    const float* __restrict__ x, u16t* __restrict__ xT)
{
  __shared__ float T[64][65];
  int s0 = blockIdx.x * 64, c0 = blockIdx.y * 64;
  int sl = threadIdx.x & 63, g = threadIdx.x >> 6;
#pragma unroll
  for (int r = 0; r < 16; ++r) {
    int cl = g + 4 * r;
    T[cl][sl] = x[(size_t)(c0 + cl) * S_LEN + s0 + sl];
  }
  __syncthreads();
  int cl2 = threadIdx.x & 63;
#pragma unroll
  for (int r = 0; r < 16; ++r) {
    int sl2 = g + 4 * r;
    xT[(size_t)(s0 + sl2) * 768 + c0 + cl2] = f2bf_u16(T[cl2][sl2]);
  }
}

// ---------------- bf16 MFMA GEMM, 128x128 tile, BK=64, gload_lds 2-phase ----
template <int WRITE_BF16>
__global__ __launch_bounds__(256) void gemm_kernel(
    const u16t* __restrict__ A, const u16t* __restrict__ Bt, void* __restrict__ Cv,
    const float* __restrict__ cosT, const float* __restrict__ sinT, int ropeRows,
    int tilesX, int tilesAll)
{
  __shared__ __align__(16) u16t smem[32768];   // [2 buf][A 8192 | B 8192] = 64 KB
  const int t = threadIdx.x;
  const int lane = t & 63, w = t >> 6;
  const int wr = w >> 1, wc = w & 1;

  const int cpx = tilesAll >> 3;
  const int nid = (blockIdx.x & 7) * cpx + (blockIdx.x >> 3);
  const int m0 = (nid / tilesX) * 128, n0 = (nid % tilesX) * 128;

  f32x4 acc[4][4];
#pragma unroll
  for (int i = 0; i < 4; ++i)
#pragma unroll
    for (int j = 0; j < 4; ++j) acc[i][j] = (f32x4){0.f, 0.f, 0.f, 0.f};

  const int rsub = w * 8 + (lane >> 3);
  const int csw  = ((lane & 7) ^ (lane >> 3)) * 8;
  const u16t* gA = A  + (size_t)(m0 + rsub) * 768 + csw;
  const u16t* gB = Bt + (size_t)(n0 + rsub) * 768 + csw;
  u16t* lb0 = smem;
  u16t* lb1 = smem + 16384;

#pragma unroll
  for (int cc = 0; cc < 4; ++cc) {
    stage16(gA + (size_t)cc * (32 * 768), lb0 + (cc * 32 + w * 8) * 64);
    stage16(gB + (size_t)cc * (32 * 768), lb0 + 8192 + (cc * 32 + w * 8) * 64);
  }
  asm volatile("s_waitcnt vmcnt(0)" ::: "memory");
  __builtin_amdgcn_s_barrier();
  __builtin_amdgcn_sched_barrier(0);

  for (int kt = 0; kt < 12; ++kt) {
    u16t* cur = (kt & 1) ? lb1 : lb0;
    u16t* nxt = (kt & 1) ? lb0 : lb1;
    if (kt < 11) {
      const u16t* pA = gA + (kt + 1) * 64;
      const u16t* pB = gB + (kt + 1) * 64;
#pragma unroll
      for (int cc = 0; cc < 4; ++cc) {
        stage16(pA + (size_t)cc * (32 * 768), nxt + (cc * 32 + w * 8) * 64);
        stage16(pB + (size_t)cc * (32 * 768), nxt + 8192 + (cc * 32 + w * 8) * 64);
      }
    }
#pragma unroll
    for (int kh = 0; kh < 2; ++kh) {
      bf16x8 af[4], bg[4];
#pragma unroll
      for (int f = 0; f < 4; ++f) {
        int ra = wr * 64 + f * 16 + (lane & 15);
        int rb = wc * 64 + f * 16 + (lane & 15);
        int sg = ((kh * 4 + (lane >> 4)) ^ (lane & 7)) * 8;
        af[f] = *(const bf16x8*)(cur + ra * 64 + sg);
        bg[f] = *(const bf16x8*)(cur + 8192 + rb * 64 + sg);
      }
#pragma unroll
      for (int i = 0; i < 4; ++i)
#pragma unroll
        for (int j = 0; j < 4; ++j)
          acc[i][j] = __builtin_amdgcn_mfma_f32_16x16x32_bf16(af[i], bg[j], acc[i][j], 0, 0, 0);
    }
    asm volatile("s_waitcnt vmcnt(0)" ::: "memory");
    __builtin_amdgcn_s_barrier();
    __builtin_amdgcn_sched_barrier(0);
  }

  const int mq = m0 + wr * 64;
  if (mq < ropeRows) {
#pragma unroll
    for (int j4 = 0; j4 < 4; ++j4)
#pragma unroll
      for (int nf = 0; nf < 4; ++nf) {
        int n = n0 + wc * 64 + nf * 16 + (lane & 15);
#pragma unroll
        for (int p = 0; p < 2; ++p) {
          int fidx = p * 16 + (lane >> 4) * 4 + j4;
          float cc = cosT[fidx * S_LEN + n], ss = sinT[fidx * S_LEN + n];
          float lo = acc[p][nf][j4], hi = acc[p + 2][nf][j4];
          acc[p][nf][j4]     = lo * cc - hi * ss;
          acc[p + 2][nf][j4] = hi * cc + lo * ss;
        }
      }
  }

  __syncthreads();
  if (WRITE_BF16) {
    u16t* Cs = smem;
#pragma unroll
    for (int i = 0; i < 4; ++i)
#pragma unroll
      for (int j4 = 0; j4 < 4; ++j4) {
        int mrow = wr * 64 + i * 16 + (lane >> 4) * 4 + j4;
#pragma unroll
        for (int nf = 0; nf < 4; ++nf) {
          int col = wc * 64 + nf * 16 + (lane & 15);
          Cs[mrow * 128 + col] = f2bf_u16(acc[i][nf][j4]);
        }
      }
    __syncthreads();
    u16t* Co = (u16t*)Cv;
#pragma unroll
    for (int it = 0; it < 8; ++it) {
      int idx = it * 256 + t;
      int row = idx >> 4, ch = idx & 15;
      *(uint4*)&Co[(size_t)(m0 + row) * S_LEN + n0 + ch * 8] =
          *(const uint4*)&Cs[row * 128 + ch * 8];
    }
  } else {
    float* Cs = (float*)smem;
#pragma unroll
    for (int i = 0; i < 4; ++i)
#pragma unroll
      for (int j4 = 0; j4 < 4; ++j4) {
        int mrow = wr * 64 + i * 16 + (lane >> 4) * 4 + j4;
#pragma unroll
        for (int nf = 0; nf < 4; ++nf) {
          int col = wc * 64 + nf * 16 + (lane & 15);
          Cs[mrow * 128 + col] = acc[i][nf][j4];
        }
      }
    __syncthreads();
    float* Co = (float*)Cv;
#pragma unroll
    for (int it = 0; it < 16; ++it) {
      int idx = it * 256 + t;
      int row = idx >> 5, ch = idx & 31;
      *(float4*)&Co[(size_t)(m0 + row) * S_LEN + n0 + ch * 4] =
          *(const float4*)&Cs[row * 128 + ch * 4];
    }
  }
}

// ---------------- windowed attention via MFMA ----------------
// block = (head, 64-query tile), 4 waves; wave w owns q rows [16w,16w+16).
// K^T [192][68], Q^T [64][68] (region reused for P [64][196]), V [64][196].
#define KLD 68
#define PLD 196

__global__ __launch_bounds__(256) void attn_kernel(
    const u16t* __restrict__ qkvb, const float* __restrict__ amask,
    u16t* __restrict__ attnT)
{
  __shared__ u16t Kt[192 * KLD];    // 26112 B
  __shared__ u16t QP[64 * PLD];     // 25088 B (Q^T then P)
  __shared__ u16t Vt[64 * PLD];     // 24832 B used ([64][196])

  const int t = threadIdx.x;
  const int lane = t & 63;
  const int w = t >> 6;
  const int h = blockIdx.y;
  const int q0 = blockIdx.x * 64;
  const int kstart = q0 - 64;
  const u16t* qbase = qkvb + (size_t)(h * 64) * S_LEN;
  const u16t* kbase = qkvb + (size_t)(768 + h * 64) * S_LEN;
  const u16t* vbase = qkvb + (size_t)(1536 + h * 64) * S_LEN;

  // stage K^T[kk][d]: dword = keys (2c,2c+1) of dim d
#pragma unroll
  for (int jj = 0; jj < 24; ++jj) {
    int ii = t + jj * 256;
    int d = ii / 96, c = ii - (ii / 96) * 96;
    int key0 = kstart + 2 * c;
    u32t v = 0;
    if (key0 >= 0 && key0 < S_LEN) v = *(const u32t*)(kbase + (size_t)d * S_LEN + key0);
    Kt[(2 * c) * KLD + d]     = (u16t)(v & 0xffffu);
    Kt[(2 * c + 1) * KLD + d] = (u16t)(v >> 16);
  }
  // stage Q^T[qi][d]
#pragma unroll
  for (int jj = 0; jj < 8; ++jj) {
    int ii = t + jj * 256;
    int d = ii >> 5, c = ii & 31;
    u32t v = *(const u32t*)(qbase + (size_t)d * S_LEN + q0 + 2 * c);
    QP[(2 * c) * KLD + d]     = (u16t)(v & 0xffffu);
    QP[(2 * c + 1) * KLD + d] = (u16t)(v >> 16);
  }
  // stage V[d][kk] (natural layout, dword copy)
#pragma unroll
  for (int jj = 0; jj < 24; ++jj) {
    int ii = t + jj * 256;
    int d = ii / 96, c = ii - (ii / 96) * 96;
    int key0 = kstart + 2 * c;
    u32t v = 0;
    if (key0 >= 0 && key0 < S_LEN) v = *(const u32t*)(vbase + (size_t)d * S_LEN + key0);
    *(u32t*)&Vt[d * PLD + 2 * c] = v;
  }
  __syncthreads();

  // Q fragments for this wave's 16 q rows
  const int fr = lane & 15, fc = lane >> 4;
  bf16x8 qa[2];
#pragma unroll
  for (int kh = 0; kh < 2; ++kh)
    qa[kh] = ld_frag(&QP[(w * 16 + fr) * KLD + kh * 32 + fc * 8]);

  // QK^T: 12 ntiles x 2 kh = 24 MFMA
  f32x4 acc[12];
#pragma unroll
  for (int nt = 0; nt < 12; ++nt) acc[nt] = (f32x4){0.f, 0.f, 0.f, 0.f};
#pragma unroll
  for (int nt = 0; nt < 12; ++nt)
#pragma unroll
    for (int kh = 0; kh < 2; ++kh) {
      bf16x8 kb = ld_frag(&Kt[(nt * 16 + fr) * KLD + kh * 32 + fc * 8]);
      acc[nt] = __builtin_amdgcn_mfma_f32_16x16x32_bf16(qa[kh], kb, acc[nt], 0, 0, 0);
    }

  // mask + scale + amask; track row max (rows q = w*16 + fc*4 + r)
  float rm[4] = {-3.0e38f, -3.0e38f, -3.0e38f, -3.0e38f};
#pragma unroll
  for (int nt = 0; nt < 12; ++nt) {
    int kk = nt * 16 + fr;
    int key = kstart + kk;
#pragma unroll
    for (int r = 0; r < 4; ++r) {
      int q = w * 16 + fc * 4 + r;
      int dk = kk - q;
      bool inw = (key >= 0) && (key < S_LEN) && (dk >= 0) && (dk <= 128);
      float s = -3.0e38f;
      if (inw) s = acc[nt][r] * 0.125f + amask[(size_t)(q0 + q) * S_LEN + key];
      acc[nt][r] = s;
      rm[r] = fmaxf(rm[r], s);
    }
  }
#pragma unroll
  for (int r = 0; r < 4; ++r)
#pragma unroll
    for (int off = 1; off < 16; off <<= 1)
      rm[r] = fmaxf(rm[r], __shfl_xor(rm[r], off));

  // exp + row sum (in registers)
  float rs[4] = {0.f, 0.f, 0.f, 0.f};
#pragma unroll
  for (int nt = 0; nt < 12; ++nt)
#pragma unroll
    for (int r = 0; r < 4; ++r) {
      float e = __expf(acc[nt][r] - rm[r]);
      acc[nt][r] = e;
      rs[r] += e;
    }
#pragma unroll
  for (int r = 0; r < 4; ++r)
#pragma unroll
    for (int off = 1; off < 16; off <<= 1)
      rs[r] += __shfl_xor(rs[r], off);

  __syncthreads();   // all waves done reading Q region -> safe to write P

  // P[q][kk] bf16 (wave writes its 16 q rows, all 192 kk)
#pragma unroll
  for (int nt = 0; nt < 12; ++nt) {
    int kk = nt * 16 + fr;
#pragma unroll
    for (int r = 0; r < 4; ++r) {
      int q = w * 16 + fc * 4 + r;
      QP[q * PLD + kk] = f2bf_u16(acc[nt][r]);
    }
  }
  __syncthreads();

  // PV: O[q][d] = sum_kk P[q][kk] V[d][kk]; 6 chunks x 4 ntiles = 24 MFMA
  f32x4 acc2[4];
#pragma unroll
  for (int nt = 0; nt < 4; ++nt) acc2[nt] = (f32x4){0.f, 0.f, 0.f, 0.f};
#pragma unroll
  for (int ch = 0; ch < 6; ++ch) {
    bf16x8 pa = ld_frag(&QP[(w * 16 + fr) * PLD + ch * 32 + fc * 8]);
#pragma unroll
    for (int nt = 0; nt < 4; ++nt) {
      bf16x8 vb = ld_frag(&Vt[(nt * 16 + fr) * PLD + ch * 32 + fc * 8]);
      acc2[nt] = __builtin_amdgcn_mfma_f32_16x16x32_bf16(pa, vb, acc2[nt], 0, 0, 0);
    }
  }

  float inv[4];
#pragma unroll
  for (int r = 0; r < 4; ++r) inv[r] = 1.f / rs[r];
#pragma unroll
  for (int nt = 0; nt < 4; ++nt)
#pragma unroll
    for (int r = 0; r < 4; ++r) {
      int q = w * 16 + fc * 4 + r;
      int d = nt * 16 + fr;
      attnT[(size_t)(q0 + q) * 768 + h * 64 + d] = f2bf_u16(acc2[nt][r] * inv[r]);
    }
}

extern "C" void kernel_launch(void* const* d_in, const int* in_sizes, int n_in,
                              void* d_out, int out_size, void* d_ws, size_t ws_size,
                              hipStream_t stream) {
  const float* x     = (const float*)d_in[0];
  const int*   pos   = (const int*)d_in[1];
  const float* amask = (const float*)d_in[2];
  const float* qkvw  = (const float*)d_in[3];
  const float* outw  = (const float*)d_in[4];
  float* out = (float*)d_out;

  char* ws = (char*)d_ws;
  float* cosT   = (float*)ws;                          ws += 32 * S_LEN * 4;
  float* sinT   = (float*)ws;                          ws += 32 * S_LEN * 4;
  u16t*  xT     = (u16t*)ws;                           ws += (size_t)S_LEN * 768 * 2;
  u16t*  wq_bf  = (u16t*)ws;                           ws += (size_t)2304 * 768 * 2;
  u16t*  wo_bf  = (u16t*)ws;                           ws += (size_t)768 * 768 * 2;
  u16t*  qkv_bf = (u16t*)ws;                           ws += (size_t)2304 * S_LEN * 2;
  u16t*  attnT  = (u16t*)ws;

  rope_table_kernel<<<(32 * S_LEN) / 256, 256, 0, stream>>>(pos, cosT, sinT);
  castw_kernel<<<(2304 * 768 / 4) / 256, 256, 0, stream>>>(qkvw, wq_bf, 2304 * 768 / 4);
  castw_kernel<<<(768 * 768 / 4) / 256, 256, 0, stream>>>(outw, wo_bf, 768 * 768 / 4);
  tcast_kernel<<<dim3(64, 12), 256, 0, stream>>>(x, xT);
  gemm_kernel<1><<<576, 256, 0, stream>>>(wq_bf, xT, qkv_bf, cosT, sinT, 1536, 32, 576);
  attn_kernel<<<dim3(64, 12), 256, 0, stream>>>(qkv_bf, amask, attnT);
  gemm_kernel<0><<<192, 256, 0, stream>>>(wo_bf, attnT, out, cosT, sinT, 0, 32, 192);
}

// Round 6
// 93.782 us; speedup vs baseline: 1.3127x; 1.3127x over previous
//
#include <hip/hip_runtime.h>
#include <hip/hip_bf16.h>
#include <math.h>

#define S_LEN 4096

typedef unsigned short u16t;
typedef unsigned int u32t;
typedef __attribute__((ext_vector_type(4))) short bf16x4;
typedef __attribute__((ext_vector_type(8))) short bf16x8;
typedef __attribute__((ext_vector_type(4))) float f32x4;

__device__ __forceinline__ u16t f2bf_u16(float f) {
  union { __hip_bfloat16 h; u16t u; } r; r.h = __float2bfloat16(f); return r.u;
}

// async global->LDS, 16B per lane; LDS dest = wave-uniform base + lane*16
__device__ __forceinline__ void stage16(const u16t* g, u16t* l) {
  __builtin_amdgcn_global_load_lds(
      (const __attribute__((address_space(1))) void*)g,
      (__attribute__((address_space(3))) void*)l, 16, 0, 0);
}

// ---------------- RoPE table, layout [32 freq][4096 s] ----------------
__global__ __launch_bounds__(256) void rope_table_kernel(
    const int* __restrict__ pos, float* __restrict__ cosT, float* __restrict__ sinT)
{
  int idx = blockIdx.x * 256 + threadIdx.x;
  if (idx >= 32 * S_LEN) return;
  int j = idx >> 12, s = idx & 4095;
  double p = (double)pos[s];
  double inv = exp(-((double)(2 * j) / 64.0) * log(10000.0));
  double a = p * inv;
  cosT[idx] = (float)cos(a);
  sinT[idx] = (float)sin(a);
}

// ---------------- flat f32 -> bf16 cast (n4 float4's) ----------------
__global__ __launch_bounds__(256) void castw_kernel(
    const float* __restrict__ src, u16t* __restrict__ dst, int n4)
{
  int i = blockIdx.x * 256 + threadIdx.x;
  if (i >= n4) return;
  float4 v = ((const float4*)src)[i];
  union { u16t h[4]; uint2 u; } r;
  r.h[0] = f2bf_u16(v.x); r.h[1] = f2bf_u16(v.y);
  r.h[2] = f2bf_u16(v.z); r.h[3] = f2bf_u16(v.w);
  ((uint2*)dst)[i] = r.u;
}

// ---------------- x [768][4096] f32 -> xT [4096][768] bf16 ----------------
__global__ __launch_bounds__(256) void tcast_kernel(
    const float* __restrict__ x, u16t* __restrict__ xT)
{
  __shared__ float T[64][65];
  int s0 = blockIdx.x * 64, c0 = blockIdx.y * 64;
  int sl = threadIdx.x & 63, g = threadIdx.x >> 6;
#pragma unroll
  for (int r = 0; r < 16; ++r) {
    int cl = g + 4 * r;
    T[cl][sl] = x[(size_t)(c0 + cl) * S_LEN + s0 + sl];
  }
  __syncthreads();
  int cl2 = threadIdx.x & 63;
#pragma unroll
  for (int r = 0; r < 16; ++r) {
    int sl2 = g + 4 * r;
    xT[(size_t)(s0 + sl2) * 768 + c0 + cl2] = f2bf_u16(T[cl2][sl2]);
  }
}

// ---------------- bf16 MFMA GEMM, 128x128 tile, BK=64, gload_lds 2-phase ----
// MODE 0: C f32 natural [M][4096] -> C1
// MODE 1: m0<1536 -> C^T bf16 into qkT [4096][1536] (C1); else V natural bf16
//         into vbuf [768][4096] (C2). RoPE epilogue for m < ropeRows.
template <int MODE>
__global__ __launch_bounds__(256) void gemm_kernel(
    const u16t* __restrict__ A, const u16t* __restrict__ Bt,
    void* __restrict__ C1, void* __restrict__ C2,
    const float* __restrict__ cosT, const float* __restrict__ sinT, int ropeRows,
    int tilesX, int tilesAll)
{
  __shared__ __align__(16) u16t smem[32768];   // 64 KB
  const int t = threadIdx.x;
  const int lane = t & 63, w = t >> 6;
  const int wr = w >> 1, wc = w & 1;
  const int ln15 = lane & 15, ln4 = lane >> 4;

  const int cpx = tilesAll >> 3;
  const int nid = (blockIdx.x & 7) * cpx + (blockIdx.x >> 3);
  const int m0 = (nid / tilesX) * 128, n0 = (nid % tilesX) * 128;

  f32x4 acc[4][4];
#pragma unroll
  for (int i = 0; i < 4; ++i)
#pragma unroll
    for (int j = 0; j < 4; ++j) acc[i][j] = (f32x4){0.f, 0.f, 0.f, 0.f};

  const int rsub = w * 8 + (lane >> 3);
  const int csw  = ((lane & 7) ^ (lane >> 3)) * 8;
  const u16t* gA = A  + (size_t)(m0 + rsub) * 768 + csw;
  const u16t* gB = Bt + (size_t)(n0 + rsub) * 768 + csw;
  u16t* lb0 = smem;
  u16t* lb1 = smem + 16384;

#pragma unroll
  for (int cc = 0; cc < 4; ++cc) {
    stage16(gA + (size_t)cc * (32 * 768), lb0 + (cc * 32 + w * 8) * 64);
    stage16(gB + (size_t)cc * (32 * 768), lb0 + 8192 + (cc * 32 + w * 8) * 64);
  }
  asm volatile("s_waitcnt vmcnt(0)" ::: "memory");
  __builtin_amdgcn_s_barrier();
  __builtin_amdgcn_sched_barrier(0);

  for (int kt = 0; kt < 12; ++kt) {
    u16t* cur = (kt & 1) ? lb1 : lb0;
    u16t* nxt = (kt & 1) ? lb0 : lb1;
    if (kt < 11) {
      const u16t* pA = gA + (kt + 1) * 64;
      const u16t* pB = gB + (kt + 1) * 64;
#pragma unroll
      for (int cc = 0; cc < 4; ++cc) {
        stage16(pA + (size_t)cc * (32 * 768), nxt + (cc * 32 + w * 8) * 64);
        stage16(pB + (size_t)cc * (32 * 768), nxt + 8192 + (cc * 32 + w * 8) * 64);
      }
    }
#pragma unroll
    for (int kh = 0; kh < 2; ++kh) {
      bf16x8 af[4], bg[4];
#pragma unroll
      for (int f = 0; f < 4; ++f) {
        int ra = wr * 64 + f * 16 + ln15;
        int rb = wc * 64 + f * 16 + ln15;
        int sg = ((kh * 4 + ln4) ^ (lane & 7)) * 8;
        af[f] = *(const bf16x8*)(cur + ra * 64 + sg);
        bg[f] = *(const bf16x8*)(cur + 8192 + rb * 64 + sg);
      }
#pragma unroll
      for (int i = 0; i < 4; ++i)
#pragma unroll
        for (int j = 0; j < 4; ++j)
          acc[i][j] = __builtin_amdgcn_mfma_f32_16x16x32_bf16(af[i], bg[j], acc[i][j], 0, 0, 0);
    }
    asm volatile("s_waitcnt vmcnt(0)" ::: "memory");
    __builtin_amdgcn_s_barrier();
    __builtin_amdgcn_sched_barrier(0);
  }

  const int mq = m0 + wr * 64;
  if (mq < ropeRows) {
#pragma unroll
    for (int j4 = 0; j4 < 4; ++j4)
#pragma unroll
      for (int nf = 0; nf < 4; ++nf) {
        int n = n0 + wc * 64 + nf * 16 + ln15;
#pragma unroll
        for (int p = 0; p < 2; ++p) {
          int fidx = p * 16 + ln4 * 4 + j4;
          float cc = cosT[fidx * S_LEN + n], ss = sinT[fidx * S_LEN + n];
          float lo = acc[p][nf][j4], hi = acc[p + 2][nf][j4];
          acc[p][nf][j4]     = lo * cc - hi * ss;
          acc[p + 2][nf][j4] = hi * cc + lo * ss;
        }
      }
  }

  __syncthreads();
  if (MODE == 1 && m0 < 1536) {
    // transposed store: Cs_T[n][m], stride 136 u16 (16B-aligned rows)
    u16t* Cs = smem;
#pragma unroll
    for (int i = 0; i < 4; ++i)
#pragma unroll
      for (int nf = 0; nf < 4; ++nf) {
        int n_l = wc * 64 + nf * 16 + ln15;
        int m_l = wr * 64 + i * 16 + ln4 * 4;
        union { u16t h[4]; uint2 u2; } pk;
#pragma unroll
        for (int j4 = 0; j4 < 4; ++j4) pk.h[j4] = f2bf_u16(acc[i][nf][j4]);
        *(uint2*)(Cs + n_l * 136 + m_l) = pk.u2;
      }
    __syncthreads();
    u16t* Co = (u16t*)C1;   // qkT [4096][1536]
#pragma unroll
    for (int it = 0; it < 8; ++it) {
      int idx = it * 256 + t;
      int row = idx >> 4, ch = idx & 15;
      *(uint4*)&Co[(size_t)(n0 + row) * 1536 + m0 + ch * 8] =
          *(const uint4*)&Cs[row * 136 + ch * 8];
    }
  } else if (MODE == 1) {
    // natural bf16 store into vbuf [768][4096]
    u16t* Cs = smem;
#pragma unroll
    for (int i = 0; i < 4; ++i)
#pragma unroll
      for (int j4 = 0; j4 < 4; ++j4) {
        int mrow = wr * 64 + i * 16 + ln4 * 4 + j4;
#pragma unroll
        for (int nf = 0; nf < 4; ++nf) {
          int col = wc * 64 + nf * 16 + ln15;
          Cs[mrow * 128 + col] = f2bf_u16(acc[i][nf][j4]);
        }
      }
    __syncthreads();
    u16t* Co = (u16t*)C2;
#pragma unroll
    for (int it = 0; it < 8; ++it) {
      int idx = it * 256 + t;
      int row = idx >> 4, ch = idx & 15;
      *(uint4*)&Co[(size_t)(m0 - 1536 + row) * S_LEN + n0 + ch * 8] =
          *(const uint4*)&Cs[row * 128 + ch * 8];
    }
  } else {
    float* Cs = (float*)smem;
#pragma unroll
    for (int i = 0; i < 4; ++i)
#pragma unroll
      for (int j4 = 0; j4 < 4; ++j4) {
        int mrow = wr * 64 + i * 16 + ln4 * 4 + j4;
#pragma unroll
        for (int nf = 0; nf < 4; ++nf) {
          int col = wc * 64 + nf * 16 + ln15;
          Cs[mrow * 128 + col] = acc[i][nf][j4];
        }
      }
    __syncthreads();
    float* Co = (float*)C1;
#pragma unroll
    for (int it = 0; it < 16; ++it) {
      int idx = it * 256 + t;
      int row = idx >> 5, ch = idx & 31;
      *(float4*)&Co[(size_t)(m0 + row) * S_LEN + n0 + ch * 4] =
          *(const float4*)&Cs[row * 128 + ch * 4];
    }
  }
}

// ---------------- windowed attention via MFMA, gload_lds staging ----------------
// qkT [4096][1536] token-major Q(cols 0..767),K(768..1535); vbuf [768][4096].
// LDS: KP = Kt[192][64] (chunk-swizzled), later P[64][192]; Vt[64][192].
// 48 KB total -> 3 blocks/CU. 768 blocks, XCD-chunked.
__global__ __launch_bounds__(256) void attn_kernel(
    const u16t* __restrict__ qkT, const u16t* __restrict__ vbuf,
    const float* __restrict__ amask, u16t* __restrict__ attnT)
{
  __shared__ __align__(16) u16t sm[24576];   // 49152 B
  u16t* KP = sm;           // 12288 u16 : Kt rows stride 64, later P rows stride 192
  u16t* Vt = sm + 12288;   // 12288 u16 : rows stride 192

  const int t = threadIdx.x;
  const int lane = t & 63, w = t >> 6;
  const int fr = lane & 15, fc = lane >> 4;

  const int nid = (blockIdx.x & 7) * 96 + (blockIdx.x >> 3);
  const int h = nid / 64, qt = nid % 64;
  const int q0 = qt * 64;
  const int kstart = q0 - 64;

  // edge pre-zero (2 q-tiles per head)
  if (q0 == 0) {
    *(uint4*)(KP + t * 8) = make_uint4(0, 0, 0, 0);
    *(uint4*)(KP + 2048 + t * 8) = make_uint4(0, 0, 0, 0);
#pragma unroll
    for (int j = 0; j < 2; ++j) {
      int unit = t + 256 * j;
      *(uint4*)(Vt + (unit >> 3) * 192 + (unit & 7) * 8) = make_uint4(0, 0, 0, 0);
    }
  } else if (q0 == S_LEN - 64) {
    *(uint4*)(KP + 8192 + t * 8) = make_uint4(0, 0, 0, 0);
    *(uint4*)(KP + 10240 + t * 8) = make_uint4(0, 0, 0, 0);
#pragma unroll
    for (int j = 0; j < 2; ++j) {
      int unit = t + 256 * j;
      *(uint4*)(Vt + (unit >> 3) * 192 + 128 + (unit & 7) * 8) = make_uint4(0, 0, 0, 0);
    }
  }

  // stage K^T rows: Kt[row][ch] = G[row][ch ^ (row&7)], row = key index
  const u16t* kcolbase = qkT + 768 + h * 64;
#pragma unroll
  for (int jj = 0; jj < 6; ++jj) {
    int ii = jj * 256 + t;
    int row = ii >> 3, ch = ii & 7;
    int key = kstart + row;
    if (key >= 0 && key < S_LEN)
      stage16(kcolbase + (size_t)key * 1536 + ((ch ^ (row & 7)) * 8),
              KP + (jj * 256 + w * 64) * 8);
  }
  // stage V rows: Vt[row][ch] = G[row][(ch&24)|((ch&7)^(row&7))], row = d
#pragma unroll
  for (int jj = 0; jj < 6; ++jj) {
    int ii = jj * 256 + t;
    int row = ii / 24, ch = ii - row * 24;
    int sc = (ch & 24) | ((ch & 7) ^ (row & 7));
    int kf = kstart + sc * 8;
    if (kf >= 0 && kf < S_LEN)
      stage16(vbuf + (size_t)(h * 64 + row) * S_LEN + kf,
              Vt + (jj * 256 + w * 64) * 8);
  }
  // Q fragments direct global->reg (rows q0 + w*16 + fr)
  const u16t* qrow = qkT + (size_t)(q0 + w * 16 + fr) * 1536 + h * 64;
  bf16x8 qa0 = *(const bf16x8*)(qrow + fc * 8);
  bf16x8 qa1 = *(const bf16x8*)(qrow + 32 + fc * 8);

  __syncthreads();

  // QK^T: 12 ntiles x 2 kh
  f32x4 acc[12];
#pragma unroll
  for (int nt = 0; nt < 12; ++nt) acc[nt] = (f32x4){0.f, 0.f, 0.f, 0.f};
#pragma unroll
  for (int nt = 0; nt < 12; ++nt) {
    int row = nt * 16 + fr;
    bf16x8 kb0 = *(const bf16x8*)(KP + row * 64 + ((fc ^ (fr & 7)) * 8));
    acc[nt] = __builtin_amdgcn_mfma_f32_16x16x32_bf16(qa0, kb0, acc[nt], 0, 0, 0);
    bf16x8 kb1 = *(const bf16x8*)(KP + row * 64 + (((4 + fc) ^ (fr & 7)) * 8));
    acc[nt] = __builtin_amdgcn_mfma_f32_16x16x32_bf16(qa1, kb1, acc[nt], 0, 0, 0);
  }

  // mask + scale + amask; rows q = w*16 + fc*4 + r, cols kk = nt*16 + fr
  float rm[4] = {-3.0e38f, -3.0e38f, -3.0e38f, -3.0e38f};
#pragma unroll
  for (int nt = 0; nt < 12; ++nt) {
    int kk = nt * 16 + fr;
    int key = kstart + kk;
#pragma unroll
    for (int r = 0; r < 4; ++r) {
      int q = w * 16 + fc * 4 + r;
      int dk = kk - q;
      bool inw = (key >= 0) && (key < S_LEN) && (dk >= 0) && (dk <= 128);
      float s = -3.0e38f;
      if (inw) s = acc[nt][r] * 0.125f + amask[(size_t)(q0 + q) * S_LEN + key];
      acc[nt][r] = s;
      rm[r] = fmaxf(rm[r], s);
    }
  }
#pragma unroll
  for (int r = 0; r < 4; ++r)
#pragma unroll
    for (int off = 1; off < 16; off <<= 1)
      rm[r] = fmaxf(rm[r], __shfl_xor(rm[r], off));

  float rs[4] = {0.f, 0.f, 0.f, 0.f};
#pragma unroll
  for (int nt = 0; nt < 12; ++nt)
#pragma unroll
    for (int r = 0; r < 4; ++r) {
      float e = __expf(acc[nt][r] - rm[r]);
      acc[nt][r] = e;
      rs[r] += e;
    }
#pragma unroll
  for (int r = 0; r < 4; ++r)
#pragma unroll
    for (int off = 1; off < 16; off <<= 1)
      rs[r] += __shfl_xor(rs[r], off);

  __syncthreads();   // all waves done reading Kt -> safe to overwrite with P

  // P[q][kk] bf16, rows stride 192, chunk-swizzled like Vt
#pragma unroll
  for (int nt = 0; nt < 12; ++nt) {
    int kk = nt * 16 + fr;
    int cg = kk >> 3;
#pragma unroll
    for (int r = 0; r < 4; ++r) {
      int q = w * 16 + fc * 4 + r;
      int csw = (cg & 24) | ((cg & 7) ^ (q & 7));
      KP[q * 192 + csw * 8 + (kk & 7)] = f2bf_u16(acc[nt][r]);
    }
  }
  __syncthreads();

  // PV: O[q][d] = sum_kk P[q][kk] V[d][kk]
  f32x4 acc2[4];
#pragma unroll
  for (int nt = 0; nt < 4; ++nt) acc2[nt] = (f32x4){0.f, 0.f, 0.f, 0.f};
#pragma unroll
  for (int c32 = 0; c32 < 6; ++c32) {
    int cg = c32 * 4 + fc;
    int csA = (cg & 24) | ((cg & 7) ^ (fr & 7));
    bf16x8 pa = *(const bf16x8*)(KP + (w * 16 + fr) * 192 + csA * 8);
#pragma unroll
    for (int nt = 0; nt < 4; ++nt) {
      int d = nt * 16 + fr;
      bf16x8 vb = *(const bf16x8*)(Vt + d * 192 + csA * 8);
      acc2[nt] = __builtin_amdgcn_mfma_f32_16x16x32_bf16(pa, vb, acc2[nt], 0, 0, 0);
    }
  }

  float inv[4];
#pragma unroll
  for (int r = 0; r < 4; ++r) inv[r] = 1.f / rs[r];
#pragma unroll
  for (int nt = 0; nt < 4; ++nt)
#pragma unroll
    for (int r = 0; r < 4; ++r) {
      int q = w * 16 + fc * 4 + r;
      int d = nt * 16 + fr;
      attnT[(size_t)(q0 + q) * 768 + h * 64 + d] = f2bf_u16(acc2[nt][r] * inv[r]);
    }
}

extern "C" void kernel_launch(void* const* d_in, const int* in_sizes, int n_in,
                              void* d_out, int out_size, void* d_ws, size_t ws_size,
                              hipStream_t stream) {
  const float* x     = (const float*)d_in[0];
  const int*   pos   = (const int*)d_in[1];
  const float* amask = (const float*)d_in[2];
  const float* qkvw  = (const float*)d_in[3];
  const float* outw  = (const float*)d_in[4];
  float* out = (float*)d_out;

  char* ws = (char*)d_ws;
  float* cosT   = (float*)ws;                          ws += 32 * S_LEN * 4;
  float* sinT   = (float*)ws;                          ws += 32 * S_LEN * 4;
  u16t*  xT     = (u16t*)ws;                           ws += (size_t)S_LEN * 768 * 2;
  u16t*  wq_bf  = (u16t*)ws;                           ws += (size_t)2304 * 768 * 2;
  u16t*  wo_bf  = (u16t*)ws;                           ws += (size_t)768 * 768 * 2;
  u16t*  qkT    = (u16t*)ws;                           ws += (size_t)S_LEN * 1536 * 2;
  u16t*  vbuf   = (u16t*)ws;                           ws += (size_t)768 * S_LEN * 2;
  u16t*  attnT  = (u16t*)ws;

  rope_table_kernel<<<(32 * S_LEN) / 256, 256, 0, stream>>>(pos, cosT, sinT);
  castw_kernel<<<(2304 * 768 / 4) / 256, 256, 0, stream>>>(qkvw, wq_bf, 2304 * 768 / 4);
  castw_kernel<<<(768 * 768 / 4) / 256, 256, 0, stream>>>(outw, wo_bf, 768 * 768 / 4);
  tcast_kernel<<<dim3(64, 12), 256, 0, stream>>>(x, xT);
  gemm_kernel<1><<<576, 256, 0, stream>>>(wq_bf, xT, qkT, vbuf, cosT, sinT, 1536, 32, 576);
  attn_kernel<<<768, 256, 0, stream>>>(qkT, vbuf, amask, attnT);
  gemm_kernel<0><<<192, 256, 0, stream>>>(wo_bf, attnT, out, nullptr, cosT, sinT, 0, 32, 192);
}

// Round 7
// 88.560 us; speedup vs baseline: 1.3901x; 1.0590x over previous
//
#include <hip/hip_runtime.h>
#include <hip/hip_bf16.h>
#include <math.h>

#define S_LEN 4096

typedef unsigned short u16t;
typedef unsigned int u32t;
typedef __attribute__((ext_vector_type(4))) short bf16x4;
typedef __attribute__((ext_vector_type(8))) short bf16x8;
typedef __attribute__((ext_vector_type(4))) float f32x4;

__device__ __forceinline__ u16t f2bf_u16(float f) {
  union { __hip_bfloat16 h; u16t u; } r; r.h = __float2bfloat16(f); return r.u;
}

// async global->LDS, 16B per lane; LDS dest = wave-uniform base + lane*16
__device__ __forceinline__ void stage16(const u16t* g, u16t* l) {
  __builtin_amdgcn_global_load_lds(
      (const __attribute__((address_space(1))) void*)g,
      (__attribute__((address_space(3))) void*)l, 16, 0, 0);
}

// ---------------- RoPE table, layout [32 freq][4096 s] ----------------
__global__ __launch_bounds__(256) void rope_table_kernel(
    const int* __restrict__ pos, float* __restrict__ cosT, float* __restrict__ sinT)
{
  int idx = blockIdx.x * 256 + threadIdx.x;
  if (idx >= 32 * S_LEN) return;
  int j = idx >> 12, s = idx & 4095;
  double p = (double)pos[s];
  double inv = exp(-((double)(2 * j) / 64.0) * log(10000.0));
  double a = p * inv;
  cosT[idx] = (float)cos(a);
  sinT[idx] = (float)sin(a);
}

// ---------------- flat f32 -> bf16 cast (n4 float4's) ----------------
__global__ __launch_bounds__(256) void castw_kernel(
    const float* __restrict__ src, u16t* __restrict__ dst, int n4)
{
  int i = blockIdx.x * 256 + threadIdx.x;
  if (i >= n4) return;
  float4 v = ((const float4*)src)[i];
  union { u16t h[4]; uint2 u; } r;
  r.h[0] = f2bf_u16(v.x); r.h[1] = f2bf_u16(v.y);
  r.h[2] = f2bf_u16(v.z); r.h[3] = f2bf_u16(v.w);
  ((uint2*)dst)[i] = r.u;
}

// ---------------- x [768][4096] f32 -> xT [4096][768] bf16 ----------------
__global__ __launch_bounds__(256) void tcast_kernel(
    const float* __restrict__ x, u16t* __restrict__ xT)
{
  __shared__ float T[64][65];
  int s0 = blockIdx.x * 64, c0 = blockIdx.y * 64;
  int sl = threadIdx.x & 63, g = threadIdx.x >> 6;
#pragma unroll
  for (int r = 0; r < 16; ++r) {
    int cl = g + 4 * r;
    T[cl][sl] = x[(size_t)(c0 + cl) * S_LEN + s0 + sl];
  }
  __syncthreads();
  int cl2 = threadIdx.x & 63;
#pragma unroll
  for (int r = 0; r < 16; ++r) {
    int sl2 = g + 4 * r;
    xT[(size_t)(s0 + sl2) * 768 + c0 + cl2] = f2bf_u16(T[cl2][sl2]);
  }
}

// ---------------- bf16 MFMA GEMM, 128x128 tile, BK=64 ----------------
// Counted-vmcnt double-buffer pipeline (T4): prologue stages tiles 0,1;
// per iter: vmcnt(8) -> barrier -> compute -> barrier -> refill(kt+2).
// 2-D rectangle XCD map: XCD x owns a rectH x rectW tile rectangle.
// MODE 0: C f32 natural [M][4096] -> C1
// MODE 1: m0<1536 -> C^T bf16 into qkT [4096][1536] (C1); else V natural bf16
//         into vbuf [768][4096] (C2). RoPE epilogue for m < ropeRows.
template <int MODE>
__global__ __launch_bounds__(256) void gemm_kernel(
    const u16t* __restrict__ A, const u16t* __restrict__ Bt,
    void* __restrict__ C1, void* __restrict__ C2,
    const float* __restrict__ cosT, const float* __restrict__ sinT, int ropeRows,
    int tilesX, int rectW, int rectH)
{
  __shared__ __align__(16) u16t smem[32768];   // 64 KB
  const int t = threadIdx.x;
  const int lane = t & 63, w = t >> 6;
  const int wr = w >> 1, wc = w & 1;
  const int ln15 = lane & 15, ln4 = lane >> 4;

  // rectangle XCD mapping (grid must be multiple of 8)
  const int xcd = blockIdx.x & 7;
  const int local = blockIdx.x >> 3;
  const int nrectX = tilesX / rectW;
  const int lm = local / rectW, ln = local - lm * rectW;
  const int m0 = ((xcd / nrectX) * rectH + lm) * 128;
  const int n0 = ((xcd % nrectX) * rectW + ln) * 128;

  f32x4 acc[4][4];
#pragma unroll
  for (int i = 0; i < 4; ++i)
#pragma unroll
    for (int j = 0; j < 4; ++j) acc[i][j] = (f32x4){0.f, 0.f, 0.f, 0.f};

  const int rsub = w * 8 + (lane >> 3);
  const int csw  = ((lane & 7) ^ (lane >> 3)) * 8;
  const u16t* gA = A  + (size_t)(m0 + rsub) * 768 + csw;
  const u16t* gB = Bt + (size_t)(n0 + rsub) * 768 + csw;
  u16t* lb0 = smem;
  u16t* lb1 = smem + 16384;

  // prologue: stage K-tiles 0 and 1 (16 loads in flight per wave)
#pragma unroll
  for (int cc = 0; cc < 4; ++cc) {
    stage16(gA + (size_t)cc * (32 * 768), lb0 + (cc * 32 + w * 8) * 64);
    stage16(gB + (size_t)cc * (32 * 768), lb0 + 8192 + (cc * 32 + w * 8) * 64);
  }
#pragma unroll
  for (int cc = 0; cc < 4; ++cc) {
    stage16(gA + 64 + (size_t)cc * (32 * 768), lb1 + (cc * 32 + w * 8) * 64);
    stage16(gB + 64 + (size_t)cc * (32 * 768), lb1 + 8192 + (cc * 32 + w * 8) * 64);
  }

  for (int kt = 0; kt < 12; ++kt) {
    u16t* cur = (kt & 1) ? lb1 : lb0;
    // wait only the tile we need; keep the other 8 loads in flight
    if (kt < 11) asm volatile("s_waitcnt vmcnt(8)" ::: "memory");
    else         asm volatile("s_waitcnt vmcnt(0)" ::: "memory");
    __builtin_amdgcn_s_barrier();
    __builtin_amdgcn_sched_barrier(0);
#pragma unroll
    for (int kh = 0; kh < 2; ++kh) {
      bf16x8 af[4], bg[4];
#pragma unroll
      for (int f = 0; f < 4; ++f) {
        int ra = wr * 64 + f * 16 + ln15;
        int rb = wc * 64 + f * 16 + ln15;
        int sg = ((kh * 4 + ln4) ^ (lane & 7)) * 8;
        af[f] = *(const bf16x8*)(cur + ra * 64 + sg);
        bg[f] = *(const bf16x8*)(cur + 8192 + rb * 64 + sg);
      }
#pragma unroll
      for (int i = 0; i < 4; ++i)
#pragma unroll
        for (int j = 0; j < 4; ++j)
          acc[i][j] = __builtin_amdgcn_mfma_f32_16x16x32_bf16(af[i], bg[j], acc[i][j], 0, 0, 0);
    }
    __builtin_amdgcn_sched_barrier(0);
    __builtin_amdgcn_s_barrier();   // readers of cur are done (values in VGPRs)
    if (kt < 10) {                  // refill cur with K-tile kt+2
      const u16t* pA = gA + (kt + 2) * 64;
      const u16t* pB = gB + (kt + 2) * 64;
#pragma unroll
      for (int cc = 0; cc < 4; ++cc) {
        stage16(pA + (size_t)cc * (32 * 768), cur + (cc * 32 + w * 8) * 64);
        stage16(pB + (size_t)cc * (32 * 768), cur + 8192 + (cc * 32 + w * 8) * 64);
      }
    }
  }

  const int mq = m0 + wr * 64;
  if (mq < ropeRows) {
#pragma unroll
    for (int j4 = 0; j4 < 4; ++j4)
#pragma unroll
      for (int nf = 0; nf < 4; ++nf) {
        int n = n0 + wc * 64 + nf * 16 + ln15;
#pragma unroll
        for (int p = 0; p < 2; ++p) {
          int fidx = p * 16 + ln4 * 4 + j4;
          float cc = cosT[fidx * S_LEN + n], ss = sinT[fidx * S_LEN + n];
          float lo = acc[p][nf][j4], hi = acc[p + 2][nf][j4];
          acc[p][nf][j4]     = lo * cc - hi * ss;
          acc[p + 2][nf][j4] = hi * cc + lo * ss;
        }
      }
  }

  __syncthreads();
  if (MODE == 1 && m0 < 1536) {
    // transposed store: Cs_T[n][m], stride 136 u16 (16B-aligned rows)
    u16t* Cs = smem;
#pragma unroll
    for (int i = 0; i < 4; ++i)
#pragma unroll
      for (int nf = 0; nf < 4; ++nf) {
        int n_l = wc * 64 + nf * 16 + ln15;
        int m_l = wr * 64 + i * 16 + ln4 * 4;
        union { u16t h[4]; uint2 u2; } pk;
#pragma unroll
        for (int j4 = 0; j4 < 4; ++j4) pk.h[j4] = f2bf_u16(acc[i][nf][j4]);
        *(uint2*)(Cs + n_l * 136 + m_l) = pk.u2;
      }
    __syncthreads();
    u16t* Co = (u16t*)C1;   // qkT [4096][1536]
#pragma unroll
    for (int it = 0; it < 8; ++it) {
      int idx = it * 256 + t;
      int row = idx >> 4, ch = idx & 15;
      *(uint4*)&Co[(size_t)(n0 + row) * 1536 + m0 + ch * 8] =
          *(const uint4*)&Cs[row * 136 + ch * 8];
    }
  } else if (MODE == 1) {
    // natural bf16 store into vbuf [768][4096]
    u16t* Cs = smem;
#pragma unroll
    for (int i = 0; i < 4; ++i)
#pragma unroll
      for (int j4 = 0; j4 < 4; ++j4) {
        int mrow = wr * 64 + i * 16 + ln4 * 4 + j4;
#pragma unroll
        for (int nf = 0; nf < 4; ++nf) {
          int col = wc * 64 + nf * 16 + ln15;
          Cs[mrow * 128 + col] = f2bf_u16(acc[i][nf][j4]);
        }
      }
    __syncthreads();
    u16t* Co = (u16t*)C2;
#pragma unroll
    for (int it = 0; it < 8; ++it) {
      int idx = it * 256 + t;
      int row = idx >> 4, ch = idx & 15;
      *(uint4*)&Co[(size_t)(m0 - 1536 + row) * S_LEN + n0 + ch * 8] =
          *(const uint4*)&Cs[row * 128 + ch * 8];
    }
  } else {
    float* Cs = (float*)smem;
#pragma unroll
    for (int i = 0; i < 4; ++i)
#pragma unroll
      for (int j4 = 0; j4 < 4; ++j4) {
        int mrow = wr * 64 + i * 16 + ln4 * 4 + j4;
#pragma unroll
        for (int nf = 0; nf < 4; ++nf) {
          int col = wc * 64 + nf * 16 + ln15;
          Cs[mrow * 128 + col] = acc[i][nf][j4];
        }
      }
    __syncthreads();
    float* Co = (float*)C1;
#pragma unroll
    for (int it = 0; it < 16; ++it) {
      int idx = it * 256 + t;
      int row = idx >> 5, ch = idx & 31;
      *(float4*)&Co[(size_t)(m0 + row) * S_LEN + n0 + ch * 4] =
          *(const float4*)&Cs[row * 128 + ch * 4];
    }
  }
}

// ---------------- windowed attention via MFMA, gload_lds staging ----------------
// (unchanged from round 6)
__global__ __launch_bounds__(256) void attn_kernel(
    const u16t* __restrict__ qkT, const u16t* __restrict__ vbuf,
    const float* __restrict__ amask, u16t* __restrict__ attnT)
{
  __shared__ __align__(16) u16t sm[24576];   // 49152 B
  u16t* KP = sm;           // Kt rows stride 64, later P rows stride 192
  u16t* Vt = sm + 12288;   // rows stride 192

  const int t = threadIdx.x;
  const int lane = t & 63, w = t >> 6;
  const int fr = lane & 15, fc = lane >> 4;

  const int nid = (blockIdx.x & 7) * 96 + (blockIdx.x >> 3);
  const int h = nid / 64, qt = nid % 64;
  const int q0 = qt * 64;
  const int kstart = q0 - 64;

  if (q0 == 0) {
    *(uint4*)(KP + t * 8) = make_uint4(0, 0, 0, 0);
    *(uint4*)(KP + 2048 + t * 8) = make_uint4(0, 0, 0, 0);
#pragma unroll
    for (int j = 0; j < 2; ++j) {
      int unit = t + 256 * j;
      *(uint4*)(Vt + (unit >> 3) * 192 + (unit & 7) * 8) = make_uint4(0, 0, 0, 0);
    }
  } else if (q0 == S_LEN - 64) {
    *(uint4*)(KP + 8192 + t * 8) = make_uint4(0, 0, 0, 0);
    *(uint4*)(KP + 10240 + t * 8) = make_uint4(0, 0, 0, 0);
#pragma unroll
    for (int j = 0; j < 2; ++j) {
      int unit = t + 256 * j;
      *(uint4*)(Vt + (unit >> 3) * 192 + 128 + (unit & 7) * 8) = make_uint4(0, 0, 0, 0);
    }
  }

  const u16t* kcolbase = qkT + 768 + h * 64;
#pragma unroll
  for (int jj = 0; jj < 6; ++jj) {
    int ii = jj * 256 + t;
    int row = ii >> 3, ch = ii & 7;
    int key = kstart + row;
    if (key >= 0 && key < S_LEN)
      stage16(kcolbase + (size_t)key * 1536 + ((ch ^ (row & 7)) * 8),
              KP + (jj * 256 + w * 64) * 8);
  }
#pragma unroll
  for (int jj = 0; jj < 6; ++jj) {
    int ii = jj * 256 + t;
    int row = ii / 24, ch = ii - row * 24;
    int sc = (ch & 24) | ((ch & 7) ^ (row & 7));
    int kf = kstart + sc * 8;
    if (kf >= 0 && kf < S_LEN)
      stage16(vbuf + (size_t)(h * 64 + row) * S_LEN + kf,
              Vt + (jj * 256 + w * 64) * 8);
  }
  const u16t* qrow = qkT + (size_t)(q0 + w * 16 + fr) * 1536 + h * 64;
  bf16x8 qa0 = *(const bf16x8*)(qrow + fc * 8);
  bf16x8 qa1 = *(const bf16x8*)(qrow + 32 + fc * 8);

  __syncthreads();

  f32x4 acc[12];
#pragma unroll
  for (int nt = 0; nt < 12; ++nt) acc[nt] = (f32x4){0.f, 0.f, 0.f, 0.f};
#pragma unroll
  for (int nt = 0; nt < 12; ++nt) {
    int row = nt * 16 + fr;
    bf16x8 kb0 = *(const bf16x8*)(KP + row * 64 + ((fc ^ (fr & 7)) * 8));
    acc[nt] = __builtin_amdgcn_mfma_f32_16x16x32_bf16(qa0, kb0, acc[nt], 0, 0, 0);
    bf16x8 kb1 = *(const bf16x8*)(KP + row * 64 + (((4 + fc) ^ (fr & 7)) * 8));
    acc[nt] = __builtin_amdgcn_mfma_f32_16x16x32_bf16(qa1, kb1, acc[nt], 0, 0, 0);
  }

  float rm[4] = {-3.0e38f, -3.0e38f, -3.0e38f, -3.0e38f};
#pragma unroll
  for (int nt = 0; nt < 12; ++nt) {
    int kk = nt * 16 + fr;
    int key = kstart + kk;
#pragma unroll
    for (int r = 0; r < 4; ++r) {
      int q = w * 16 + fc * 4 + r;
      int dk = kk - q;
      bool inw = (key >= 0) && (key < S_LEN) && (dk >= 0) && (dk <= 128);
      float s = -3.0e38f;
      if (inw) s = acc[nt][r] * 0.125f + amask[(size_t)(q0 + q) * S_LEN + key];
      acc[nt][r] = s;
      rm[r] = fmaxf(rm[r], s);
    }
  }
#pragma unroll
  for (int r = 0; r < 4; ++r)
#pragma unroll
    for (int off = 1; off < 16; off <<= 1)
      rm[r] = fmaxf(rm[r], __shfl_xor(rm[r], off));

  float rs[4] = {0.f, 0.f, 0.f, 0.f};
#pragma unroll
  for (int nt = 0; nt < 12; ++nt)
#pragma unroll
    for (int r = 0; r < 4; ++r) {
      float e = __expf(acc[nt][r] - rm[r]);
      acc[nt][r] = e;
      rs[r] += e;
    }
#pragma unroll
  for (int r = 0; r < 4; ++r)
#pragma unroll
    for (int off = 1; off < 16; off <<= 1)
      rs[r] += __shfl_xor(rs[r], off);

  __syncthreads();

#pragma unroll
  for (int nt = 0; nt < 12; ++nt) {
    int kk = nt * 16 + fr;
    int cg = kk >> 3;
#pragma unroll
    for (int r = 0; r < 4; ++r) {
      int q = w * 16 + fc * 4 + r;
      int csw = (cg & 24) | ((cg & 7) ^ (q & 7));
      KP[q * 192 + csw * 8 + (kk & 7)] = f2bf_u16(acc[nt][r]);
    }
  }
  __syncthreads();

  f32x4 acc2[4];
#pragma unroll
  for (int nt = 0; nt < 4; ++nt) acc2[nt] = (f32x4){0.f, 0.f, 0.f, 0.f};
#pragma unroll
  for (int c32 = 0; c32 < 6; ++c32) {
    int cg = c32 * 4 + fc;
    int csA = (cg & 24) | ((cg & 7) ^ (fr & 7));
    bf16x8 pa = *(const bf16x8*)(KP + (w * 16 + fr) * 192 + csA * 8);
#pragma unroll
    for (int nt = 0; nt < 4; ++nt) {
      int d = nt * 16 + fr;
      bf16x8 vb = *(const bf16x8*)(Vt + d * 192 + csA * 8);
      acc2[nt] = __builtin_amdgcn_mfma_f32_16x16x32_bf16(pa, vb, acc2[nt], 0, 0, 0);
    }
  }

  float inv[4];
#pragma unroll
  for (int r = 0; r < 4; ++r) inv[r] = 1.f / rs[r];
#pragma unroll
  for (int nt = 0; nt < 4; ++nt)
#pragma unroll
    for (int r = 0; r < 4; ++r) {
      int q = w * 16 + fc * 4 + r;
      int d = nt * 16 + fr;
      attnT[(size_t)(q0 + q) * 768 + h * 64 + d] = f2bf_u16(acc2[nt][r] * inv[r]);
    }
}

extern "C" void kernel_launch(void* const* d_in, const int* in_sizes, int n_in,
                              void* d_out, int out_size, void* d_ws, size_t ws_size,
                              hipStream_t stream) {
  const float* x     = (const float*)d_in[0];
  const int*   pos   = (const int*)d_in[1];
  const float* amask = (const float*)d_in[2];
  const float* qkvw  = (const float*)d_in[3];
  const float* outw  = (const float*)d_in[4];
  float* out = (float*)d_out;

  char* ws = (char*)d_ws;
  float* cosT   = (float*)ws;                          ws += 32 * S_LEN * 4;
  float* sinT   = (float*)ws;                          ws += 32 * S_LEN * 4;
  u16t*  xT     = (u16t*)ws;                           ws += (size_t)S_LEN * 768 * 2;
  u16t*  wq_bf  = (u16t*)ws;                           ws += (size_t)2304 * 768 * 2;
  u16t*  wo_bf  = (u16t*)ws;                           ws += (size_t)768 * 768 * 2;
  u16t*  qkT    = (u16t*)ws;                           ws += (size_t)S_LEN * 1536 * 2;
  u16t*  vbuf   = (u16t*)ws;                           ws += (size_t)768 * S_LEN * 2;
  u16t*  attnT  = (u16t*)ws;

  rope_table_kernel<<<(32 * S_LEN) / 256, 256, 0, stream>>>(pos, cosT, sinT);
  castw_kernel<<<(2304 * 768 / 4) / 256, 256, 0, stream>>>(qkvw, wq_bf, 2304 * 768 / 4);
  castw_kernel<<<(768 * 768 / 4) / 256, 256, 0, stream>>>(outw, wo_bf, 768 * 768 / 4);
  tcast_kernel<<<dim3(64, 12), 256, 0, stream>>>(x, xT);
  // QKV: 18x32 tiles, XCD rect = 9m x 8n
  gemm_kernel<1><<<576, 256, 0, stream>>>(wq_bf, xT, qkT, vbuf, cosT, sinT, 1536, 32, 8, 9);
  attn_kernel<<<768, 256, 0, stream>>>(qkT, vbuf, amask, attnT);
  // out-proj: 6x32 tiles, XCD rect = 6m x 4n
  gemm_kernel<0><<<192, 256, 0, stream>>>(wo_bf, attnT, out, nullptr, cosT, sinT, 0, 32, 4, 6);
}

// Round 8
// 79.499 us; speedup vs baseline: 1.5485x; 1.1140x over previous
//
#include <hip/hip_runtime.h>
#include <hip/hip_bf16.h>
#include <math.h>

#define S_LEN 4096

typedef unsigned short u16t;
typedef unsigned int u32t;
typedef __attribute__((ext_vector_type(4))) short bf16x4;
typedef __attribute__((ext_vector_type(8))) short bf16x8;
typedef __attribute__((ext_vector_type(4))) float f32x4;

__device__ __forceinline__ u16t f2bf_u16(float f) {
  union { __hip_bfloat16 h; u16t u; } r; r.h = __float2bfloat16(f); return r.u;
}

// async global->LDS, 16B per lane; LDS dest = wave-uniform base + lane*16
__device__ __forceinline__ void stage16(const u16t* g, u16t* l) {
  __builtin_amdgcn_global_load_lds(
      (const __attribute__((address_space(1))) void*)g,
      (__attribute__((address_space(3))) void*)l, 16, 0, 0);
}

// ---------------- fused prep: tcast | castw(wq) | castw(wo) | rope ----------------
// blocks [0,768): x [768][4096] f32 -> xT [4096][768] bf16
// blocks [768,2496): qkvw f32 -> wq bf16 (442368 uint2)
// blocks [2496,3072): outw f32 -> wo bf16 (147456 uint2)
// blocks [3072,3584): RoPE table [32 freq][4096 s]
__global__ __launch_bounds__(256) void prep_kernel(
    const float* __restrict__ x, u16t* __restrict__ xT,
    const float* __restrict__ qkvw, u16t* __restrict__ wq,
    const float* __restrict__ outw, u16t* __restrict__ wo,
    const int* __restrict__ pos, float* __restrict__ cosT, float* __restrict__ sinT)
{
  __shared__ float T[64][65];
  const int b = blockIdx.x;
  const int t = threadIdx.x;
  if (b < 768) {
    int s0 = (b & 63) * 64, c0 = (b >> 6) * 64;
    int sl = t & 63, g = t >> 6;
#pragma unroll
    for (int r = 0; r < 16; ++r) {
      int cl = g + 4 * r;
      T[cl][sl] = x[(size_t)(c0 + cl) * S_LEN + s0 + sl];
    }
    __syncthreads();
#pragma unroll
    for (int r = 0; r < 16; ++r) {
      int sl2 = g + 4 * r;
      xT[(size_t)(s0 + sl2) * 768 + c0 + sl] = f2bf_u16(T[sl][sl2]);
    }
  } else if (b < 3072) {
    const float* src; u16t* dst; int i;
    if (b < 2496) { src = qkvw; dst = wq; i = (b - 768) * 256 + t; }
    else          { src = outw; dst = wo; i = (b - 2496) * 256 + t; }
    float4 v = ((const float4*)src)[i];
    union { u16t h[4]; uint2 u; } r;
    r.h[0] = f2bf_u16(v.x); r.h[1] = f2bf_u16(v.y);
    r.h[2] = f2bf_u16(v.z); r.h[3] = f2bf_u16(v.w);
    ((uint2*)dst)[i] = r.u;
  } else {
    int idx = (b - 3072) * 256 + t;
    int j = idx >> 12, s = idx & 4095;
    double p = (double)pos[s];
    double inv = exp(-((double)(2 * j) / 64.0) * log(10000.0));
    double a = p * inv;
    cosT[idx] = (float)cos(a);
    sinT[idx] = (float)sin(a);
  }
}

// ---------------- bf16 MFMA GEMM, 128x128 tile, BK=64 ----------------
// Counted-vmcnt double-buffer pipeline: prologue stages tiles 0,1;
// per iter: vmcnt(8) -> barrier -> compute -> barrier -> refill(kt+2).
// 2-D rectangle XCD map: XCD x owns a rectH x rectW tile rectangle.
// MODE 0: C f32 natural [M][4096] -> C1
// MODE 1: m0<1536 -> C^T bf16 into qkT [4096][1536] (C1); else V natural bf16
//         into vbuf [768][4096] (C2). RoPE epilogue for m < ropeRows.
template <int MODE>
__global__ __launch_bounds__(256) void gemm_kernel(
    const u16t* __restrict__ A, const u16t* __restrict__ Bt,
    void* __restrict__ C1, void* __restrict__ C2,
    const float* __restrict__ cosT, const float* __restrict__ sinT, int ropeRows,
    int tilesX, int rectW, int rectH)
{
  __shared__ __align__(16) u16t smem[32768];   // 64 KB
  const int t = threadIdx.x;
  const int lane = t & 63, w = t >> 6;
  const int wr = w >> 1, wc = w & 1;
  const int ln15 = lane & 15, ln4 = lane >> 4;

  // rectangle XCD mapping (grid must be multiple of 8)
  const int xcd = blockIdx.x & 7;
  const int local = blockIdx.x >> 3;
  const int nrectX = tilesX / rectW;
  const int lm = local / rectW, ln = local - lm * rectW;
  const int m0 = ((xcd / nrectX) * rectH + lm) * 128;
  const int n0 = ((xcd % nrectX) * rectW + ln) * 128;

  f32x4 acc[4][4];
#pragma unroll
  for (int i = 0; i < 4; ++i)
#pragma unroll
    for (int j = 0; j < 4; ++j) acc[i][j] = (f32x4){0.f, 0.f, 0.f, 0.f};

  const int rsub = w * 8 + (lane >> 3);
  const int csw  = ((lane & 7) ^ (lane >> 3)) * 8;
  const u16t* gA = A  + (size_t)(m0 + rsub) * 768 + csw;
  const u16t* gB = Bt + (size_t)(n0 + rsub) * 768 + csw;
  u16t* lb0 = smem;
  u16t* lb1 = smem + 16384;

  // prologue: stage K-tiles 0 and 1 (16 loads in flight per wave)
#pragma unroll
  for (int cc = 0; cc < 4; ++cc) {
    stage16(gA + (size_t)cc * (32 * 768), lb0 + (cc * 32 + w * 8) * 64);
    stage16(gB + (size_t)cc * (32 * 768), lb0 + 8192 + (cc * 32 + w * 8) * 64);
  }
#pragma unroll
  for (int cc = 0; cc < 4; ++cc) {
    stage16(gA + 64 + (size_t)cc * (32 * 768), lb1 + (cc * 32 + w * 8) * 64);
    stage16(gB + 64 + (size_t)cc * (32 * 768), lb1 + 8192 + (cc * 32 + w * 8) * 64);
  }

  for (int kt = 0; kt < 12; ++kt) {
    u16t* cur = (kt & 1) ? lb1 : lb0;
    // wait only the tile we need; keep the other 8 loads in flight
    if (kt < 11) asm volatile("s_waitcnt vmcnt(8)" ::: "memory");
    else         asm volatile("s_waitcnt vmcnt(0)" ::: "memory");
    __builtin_amdgcn_s_barrier();
#pragma unroll
    for (int kh = 0; kh < 2; ++kh) {
      bf16x8 af[4], bg[4];
#pragma unroll
      for (int f = 0; f < 4; ++f) {
        int ra = wr * 64 + f * 16 + ln15;
        int rb = wc * 64 + f * 16 + ln15;
        int sg = ((kh * 4 + ln4) ^ (lane & 7)) * 8;
        af[f] = *(const bf16x8*)(cur + ra * 64 + sg);
        bg[f] = *(const bf16x8*)(cur + 8192 + rb * 64 + sg);
      }
#pragma unroll
      for (int i = 0; i < 4; ++i)
#pragma unroll
        for (int j = 0; j < 4; ++j)
          acc[i][j] = __builtin_amdgcn_mfma_f32_16x16x32_bf16(af[i], bg[j], acc[i][j], 0, 0, 0);
    }
    __builtin_amdgcn_s_barrier();   // readers of cur are done (values in VGPRs)
    if (kt < 10) {                  // refill cur with K-tile kt+2
      const u16t* pA = gA + (kt + 2) * 64;
      const u16t* pB = gB + (kt + 2) * 64;
#pragma unroll
      for (int cc = 0; cc < 4; ++cc) {
        stage16(pA + (size_t)cc * (32 * 768), cur + (cc * 32 + w * 8) * 64);
        stage16(pB + (size_t)cc * (32 * 768), cur + 8192 + (cc * 32 + w * 8) * 64);
      }
    }
  }

  const int mq = m0 + wr * 64;
  if (mq < ropeRows) {
#pragma unroll
    for (int j4 = 0; j4 < 4; ++j4)
#pragma unroll
      for (int nf = 0; nf < 4; ++nf) {
        int n = n0 + wc * 64 + nf * 16 + ln15;
#pragma unroll
        for (int p = 0; p < 2; ++p) {
          int fidx = p * 16 + ln4 * 4 + j4;
          float cc = cosT[fidx * S_LEN + n], ss = sinT[fidx * S_LEN + n];
          float lo = acc[p][nf][j4], hi = acc[p + 2][nf][j4];
          acc[p][nf][j4]     = lo * cc - hi * ss;
          acc[p + 2][nf][j4] = hi * cc + lo * ss;
        }
      }
  }

  __syncthreads();
  if (MODE == 1 && m0 < 1536) {
    // transposed store: Cs_T[n][m], stride 136 u16 (16B-aligned rows)
    u16t* Cs = smem;
#pragma unroll
    for (int i = 0; i < 4; ++i)
#pragma unroll
      for (int nf = 0; nf < 4; ++nf) {
        int n_l = wc * 64 + nf * 16 + ln15;
        int m_l = wr * 64 + i * 16 + ln4 * 4;
        union { u16t h[4]; uint2 u2; } pk;
#pragma unroll
        for (int j4 = 0; j4 < 4; ++j4) pk.h[j4] = f2bf_u16(acc[i][nf][j4]);
        *(uint2*)(Cs + n_l * 136 + m_l) = pk.u2;
      }
    __syncthreads();
    u16t* Co = (u16t*)C1;   // qkT [4096][1536]
#pragma unroll
    for (int it = 0; it < 8; ++it) {
      int idx = it * 256 + t;
      int row = idx >> 4, ch = idx & 15;
      *(uint4*)&Co[(size_t)(n0 + row) * 1536 + m0 + ch * 8] =
          *(const uint4*)&Cs[row * 136 + ch * 8];
    }
  } else if (MODE == 1) {
    // natural bf16 store into vbuf [768][4096]
    u16t* Cs = smem;
#pragma unroll
    for (int i = 0; i < 4; ++i)
#pragma unroll
      for (int j4 = 0; j4 < 4; ++j4) {
        int mrow = wr * 64 + i * 16 + ln4 * 4 + j4;
#pragma unroll
        for (int nf = 0; nf < 4; ++nf) {
          int col = wc * 64 + nf * 16 + ln15;
          Cs[mrow * 128 + col] = f2bf_u16(acc[i][nf][j4]);
        }
      }
    __syncthreads();
    u16t* Co = (u16t*)C2;
#pragma unroll
    for (int it = 0; it < 8; ++it) {
      int idx = it * 256 + t;
      int row = idx >> 4, ch = idx & 15;
      *(uint4*)&Co[(size_t)(m0 - 1536 + row) * S_LEN + n0 + ch * 8] =
          *(const uint4*)&Cs[row * 128 + ch * 8];
    }
  } else {
    float* Cs = (float*)smem;
#pragma unroll
    for (int i = 0; i < 4; ++i)
#pragma unroll
      for (int j4 = 0; j4 < 4; ++j4) {
        int mrow = wr * 64 + i * 16 + ln4 * 4 + j4;
#pragma unroll
        for (int nf = 0; nf < 4; ++nf) {
          int col = wc * 64 + nf * 16 + ln15;
          Cs[mrow * 128 + col] = acc[i][nf][j4];
        }
      }
    __syncthreads();
    float* Co = (float*)C1;
#pragma unroll
    for (int it = 0; it < 16; ++it) {
      int idx = it * 256 + t;
      int row = idx >> 5, ch = idx & 31;
      *(float4*)&Co[(size_t)(m0 + row) * S_LEN + n0 + ch * 4] =
          *(const float4*)&Cs[row * 128 + ch * 4];
    }
  }
}

// ---------------- windowed attention via MFMA, gload_lds staging ----------------
// round-7 structure + setprio around MFMA clusters + 3rd barrier removed
// (each wave's PV reads only the P rows it wrote; within-wave RAW is lgkm-ordered)
__global__ __launch_bounds__(256) void attn_kernel(
    const u16t* __restrict__ qkT, const u16t* __restrict__ vbuf,
    const float* __restrict__ amask, u16t* __restrict__ attnT)
{
  __shared__ __align__(16) u16t sm[24576];   // 49152 B
  u16t* KP = sm;           // Kt rows stride 64, later P rows stride 192
  u16t* Vt = sm + 12288;   // rows stride 192

  const int t = threadIdx.x;
  const int lane = t & 63, w = t >> 6;
  const int fr = lane & 15, fc = lane >> 4;

  const int nid = (blockIdx.x & 7) * 96 + (blockIdx.x >> 3);
  const int h = nid / 64, qt = nid % 64;
  const int q0 = qt * 64;
  const int kstart = q0 - 64;

  if (q0 == 0) {
    *(uint4*)(KP + t * 8) = make_uint4(0, 0, 0, 0);
    *(uint4*)(KP + 2048 + t * 8) = make_uint4(0, 0, 0, 0);
#pragma unroll
    for (int j = 0; j < 2; ++j) {
      int unit = t + 256 * j;
      *(uint4*)(Vt + (unit >> 3) * 192 + (unit & 7) * 8) = make_uint4(0, 0, 0, 0);
    }
  } else if (q0 == S_LEN - 64) {
    *(uint4*)(KP + 8192 + t * 8) = make_uint4(0, 0, 0, 0);
    *(uint4*)(KP + 10240 + t * 8) = make_uint4(0, 0, 0, 0);
#pragma unroll
    for (int j = 0; j < 2; ++j) {
      int unit = t + 256 * j;
      *(uint4*)(Vt + (unit >> 3) * 192 + 128 + (unit & 7) * 8) = make_uint4(0, 0, 0, 0);
    }
  }

  const u16t* kcolbase = qkT + 768 + h * 64;
#pragma unroll
  for (int jj = 0; jj < 6; ++jj) {
    int ii = jj * 256 + t;
    int row = ii >> 3, ch = ii & 7;
    int key = kstart + row;
    if (key >= 0 && key < S_LEN)
      stage16(kcolbase + (size_t)key * 1536 + ((ch ^ (row & 7)) * 8),
              KP + (jj * 256 + w * 64) * 8);
  }
#pragma unroll
  for (int jj = 0; jj < 6; ++jj) {
    int ii = jj * 256 + t;
    int row = ii / 24, ch = ii - row * 24;
    int sc = (ch & 24) | ((ch & 7) ^ (row & 7));
    int kf = kstart + sc * 8;
    if (kf >= 0 && kf < S_LEN)
      stage16(vbuf + (size_t)(h * 64 + row) * S_LEN + kf,
              Vt + (jj * 256 + w * 64) * 8);
  }
  const u16t* qrow = qkT + (size_t)(q0 + w * 16 + fr) * 1536 + h * 64;
  bf16x8 qa0 = *(const bf16x8*)(qrow + fc * 8);
  bf16x8 qa1 = *(const bf16x8*)(qrow + 32 + fc * 8);

  __syncthreads();

  f32x4 acc[12];
#pragma unroll
  for (int nt = 0; nt < 12; ++nt) acc[nt] = (f32x4){0.f, 0.f, 0.f, 0.f};
  __builtin_amdgcn_s_setprio(1);
#pragma unroll
  for (int nt = 0; nt < 12; ++nt) {
    int row = nt * 16 + fr;
    bf16x8 kb0 = *(const bf16x8*)(KP + row * 64 + ((fc ^ (fr & 7)) * 8));
    acc[nt] = __builtin_amdgcn_mfma_f32_16x16x32_bf16(qa0, kb0, acc[nt], 0, 0, 0);
    bf16x8 kb1 = *(const bf16x8*)(KP + row * 64 + (((4 + fc) ^ (fr & 7)) * 8));
    acc[nt] = __builtin_amdgcn_mfma_f32_16x16x32_bf16(qa1, kb1, acc[nt], 0, 0, 0);
  }
  __builtin_amdgcn_s_setprio(0);

  float rm[4] = {-3.0e38f, -3.0e38f, -3.0e38f, -3.0e38f};
#pragma unroll
  for (int nt = 0; nt < 12; ++nt) {
    int kk = nt * 16 + fr;
    int key = kstart + kk;
#pragma unroll
    for (int r = 0; r < 4; ++r) {
      int q = w * 16 + fc * 4 + r;
      int dk = kk - q;
      bool inw = (key >= 0) && (key < S_LEN) && (dk >= 0) && (dk <= 128);
      float s = -3.0e38f;
      if (inw) s = acc[nt][r] * 0.125f + amask[(size_t)(q0 + q) * S_LEN + key];
      acc[nt][r] = s;
      rm[r] = fmaxf(rm[r], s);
    }
  }
#pragma unroll
  for (int r = 0; r < 4; ++r)
#pragma unroll
    for (int off = 1; off < 16; off <<= 1)
      rm[r] = fmaxf(rm[r], __shfl_xor(rm[r], off));

  float rs[4] = {0.f, 0.f, 0.f, 0.f};
#pragma unroll
  for (int nt = 0; nt < 12; ++nt)
#pragma unroll
    for (int r = 0; r < 4; ++r) {
      float e = __expf(acc[nt][r] - rm[r]);
      acc[nt][r] = e;
      rs[r] += e;
    }
#pragma unroll
  for (int r = 0; r < 4; ++r)
#pragma unroll
    for (int off = 1; off < 16; off <<= 1)
      rs[r] += __shfl_xor(rs[r], off);

  __syncthreads();   // all waves done reading Kt -> safe to overwrite with P

#pragma unroll
  for (int nt = 0; nt < 12; ++nt) {
    int kk = nt * 16 + fr;
    int cg = kk >> 3;
#pragma unroll
    for (int r = 0; r < 4; ++r) {
      int q = w * 16 + fc * 4 + r;
      int csw = (cg & 24) | ((cg & 7) ^ (q & 7));
      KP[q * 192 + csw * 8 + (kk & 7)] = f2bf_u16(acc[nt][r]);
    }
  }
  // no barrier: PV below reads only rows [w*16, w*16+16) of P, written by this wave

  f32x4 acc2[4];
#pragma unroll
  for (int nt = 0; nt < 4; ++nt) acc2[nt] = (f32x4){0.f, 0.f, 0.f, 0.f};
  __builtin_amdgcn_s_setprio(1);
#pragma unroll
  for (int c32 = 0; c32 < 6; ++c32) {
    int cg = c32 * 4 + fc;
    int csA = (cg & 24) | ((cg & 7) ^ (fr & 7));
    bf16x8 pa = *(const bf16x8*)(KP + (w * 16 + fr) * 192 + csA * 8);
#pragma unroll
    for (int nt = 0; nt < 4; ++nt) {
      int d = nt * 16 + fr;
      bf16x8 vb = *(const bf16x8*)(Vt + d * 192 + csA * 8);
      acc2[nt] = __builtin_amdgcn_mfma_f32_16x16x32_bf16(pa, vb, acc2[nt], 0, 0, 0);
    }
  }
  __builtin_amdgcn_s_setprio(0);

  float inv[4];
#pragma unroll
  for (int r = 0; r < 4; ++r) inv[r] = 1.f / rs[r];
#pragma unroll
  for (int nt = 0; nt < 4; ++nt)
#pragma unroll
    for (int r = 0; r < 4; ++r) {
      int q = w * 16 + fc * 4 + r;
      int d = nt * 16 + fr;
      attnT[(size_t)(q0 + q) * 768 + h * 64 + d] = f2bf_u16(acc2[nt][r] * inv[r]);
    }
}

extern "C" void kernel_launch(void* const* d_in, const int* in_sizes, int n_in,
                              void* d_out, int out_size, void* d_ws, size_t ws_size,
                              hipStream_t stream) {
  const float* x     = (const float*)d_in[0];
  const int*   pos   = (const int*)d_in[1];
  const float* amask = (const float*)d_in[2];
  const float* qkvw  = (const float*)d_in[3];
  const float* outw  = (const float*)d_in[4];
  float* out = (float*)d_out;

  char* ws = (char*)d_ws;
  float* cosT   = (float*)ws;                          ws += 32 * S_LEN * 4;
  float* sinT   = (float*)ws;                          ws += 32 * S_LEN * 4;
  u16t*  xT     = (u16t*)ws;                           ws += (size_t)S_LEN * 768 * 2;
  u16t*  wq_bf  = (u16t*)ws;                           ws += (size_t)2304 * 768 * 2;
  u16t*  wo_bf  = (u16t*)ws;                           ws += (size_t)768 * 768 * 2;
  u16t*  qkT    = (u16t*)ws;                           ws += (size_t)S_LEN * 1536 * 2;
  u16t*  vbuf   = (u16t*)ws;                           ws += (size_t)768 * S_LEN * 2;
  u16t*  attnT  = (u16t*)ws;

  // fused prep: tcast(768) | castw wq(1728) | castw wo(576) | rope(512)
  prep_kernel<<<3584, 256, 0, stream>>>(x, xT, qkvw, wq_bf, outw, wo_bf, pos, cosT, sinT);
  // QKV: 18x32 tiles, XCD rect = 9m x 8n
  gemm_kernel<1><<<576, 256, 0, stream>>>(wq_bf, xT, qkT, vbuf, cosT, sinT, 1536, 32, 8, 9);
  attn_kernel<<<768, 256, 0, stream>>>(qkT, vbuf, amask, attnT);
  // out-proj: 6x32 tiles, XCD rect = 6m x 4n
  gemm_kernel<0><<<192, 256, 0, stream>>>(wo_bf, attnT, out, nullptr, cosT, sinT, 0, 32, 4, 6);
}

// Round 10
// 72.109 us; speedup vs baseline: 1.7072x; 1.1025x over previous
//
#include <hip/hip_runtime.h>
#include <hip/hip_bf16.h>
#include <math.h>

#define S_LEN 4096

typedef unsigned short u16t;
typedef unsigned int u32t;
typedef __attribute__((ext_vector_type(4))) short bf16x4;
typedef __attribute__((ext_vector_type(8))) short bf16x8;
typedef __attribute__((ext_vector_type(4))) float f32x4;

__device__ __forceinline__ u16t f2bf_u16(float f) {
  union { __hip_bfloat16 h; u16t u; } r; r.h = __float2bfloat16(f); return r.u;
}

// async global->LDS, 16B per lane; LDS dest = wave-uniform base + lane*16
__device__ __forceinline__ void stage16(const u16t* g, u16t* l) {
  __builtin_amdgcn_global_load_lds(
      (const __attribute__((address_space(1))) void*)g,
      (__attribute__((address_space(3))) void*)l, 16, 0, 0);
}

// ---------------- fused prep: tcast | castw(wq) | castw(wo) | rope ----------------
__global__ __launch_bounds__(256) void prep_kernel(
    const float* __restrict__ x, u16t* __restrict__ xT,
    const float* __restrict__ qkvw, u16t* __restrict__ wq,
    const float* __restrict__ outw, u16t* __restrict__ wo,
    const int* __restrict__ pos, float* __restrict__ cosT, float* __restrict__ sinT)
{
  __shared__ float T[64][65];
  const int b = blockIdx.x;
  const int t = threadIdx.x;
  if (b < 768) {
    int s0 = (b & 63) * 64, c0 = (b >> 6) * 64;
    int sl = t & 63, g = t >> 6;
#pragma unroll
    for (int r = 0; r < 16; ++r) {
      int cl = g + 4 * r;
      T[cl][sl] = x[(size_t)(c0 + cl) * S_LEN + s0 + sl];
    }
    __syncthreads();
#pragma unroll
    for (int r = 0; r < 16; ++r) {
      int sl2 = g + 4 * r;
      xT[(size_t)(s0 + sl2) * 768 + c0 + sl] = f2bf_u16(T[sl][sl2]);
    }
  } else if (b < 3072) {
    const float* src; u16t* dst; int i;
    if (b < 2496) { src = qkvw; dst = wq; i = (b - 768) * 256 + t; }
    else          { src = outw; dst = wo; i = (b - 2496) * 256 + t; }
    float4 v = ((const float4*)src)[i];
    union { u16t h[4]; uint2 u; } r;
    r.h[0] = f2bf_u16(v.x); r.h[1] = f2bf_u16(v.y);
    r.h[2] = f2bf_u16(v.z); r.h[3] = f2bf_u16(v.w);
    ((uint2*)dst)[i] = r.u;
  } else {
    int idx = (b - 3072) * 256 + t;
    int j = idx >> 12, s = idx & 4095;
    double p = (double)pos[s];
    double inv = exp(-((double)(2 * j) / 64.0) * log(10000.0));
    double a = p * inv;
    cosT[idx] = (float)cos(a);
    sinT[idx] = (float)sin(a);
  }
}

// ---------------- bf16 MFMA GEMM, 128x128 tile, BK=32, 3 blocks/CU ----------------
// Counted-vmcnt double-buffer: prologue stages K-tiles 0,1; per iter:
// vmcnt(4) -> barrier -> SCHED_PIN -> 16 MFMA -> SCHED_PIN -> barrier ->
// SCHED_PIN -> refill(kt+2). sched_barrier(0) pins are REQUIRED: raw s_barrier
// has no compiler memory semantics; without pins the scheduler may hoist
// ds_reads above barrier (reads rows staged by OTHER waves) or hoist the
// refill above the second barrier (overwrites rows other waves still read).
// Round-9 failure (absmax 7e-2) was exactly this hazard.
// MODE 0: C f32 natural [M][4096] -> C1 (direct coalesced stores)
// MODE 1: m0<1536 -> C^T bf16 into qkT [4096][1536] (C1); else V natural bf16
//         into vbuf [768][4096] (C2). RoPE epilogue for m < ropeRows.
template <int MODE>
__global__ __launch_bounds__(256, 3) void gemm_kernel(
    const u16t* __restrict__ A, const u16t* __restrict__ Bt,
    void* __restrict__ C1, void* __restrict__ C2,
    const float* __restrict__ cosT, const float* __restrict__ sinT, int ropeRows,
    int tilesX, int rectW, int rectH)
{
  __shared__ __align__(16) u16t smem[17408];   // 34.8 KB (K-loop uses first 32 KB)
  const int t = threadIdx.x;
  const int lane = t & 63, w = t >> 6;
  const int wr = w >> 1, wc = w & 1;
  const int ln15 = lane & 15, ln4 = lane >> 4;

  // rectangle XCD mapping (grid must be multiple of 8)
  const int xcd = blockIdx.x & 7;
  const int local = blockIdx.x >> 3;
  const int nrectX = tilesX / rectW;
  const int lm = local / rectW, ln = local - lm * rectW;
  const int m0 = ((xcd / nrectX) * rectH + lm) * 128;
  const int n0 = ((xcd % nrectX) * rectW + ln) * 128;

  f32x4 acc[4][4];
#pragma unroll
  for (int i = 0; i < 4; ++i)
#pragma unroll
    for (int j = 0; j < 4; ++j) acc[i][j] = (f32x4){0.f, 0.f, 0.f, 0.f};

  // staging: thread covers rows w*32+(lane>>2) and +16; slot = lane&3.
  // LDS[row][slot] = G[row][slot ^ ((row>>1)&3)]; (row>>1)&3 == (lane>>3)&3.
  const int srow = w * 32 + (lane >> 2);
  const int sch  = ((lane & 3) ^ ((lane >> 3) & 3)) * 8;
  const u16t* gA0 = A  + (size_t)(m0 + srow) * 768 + sch;
  const u16t* gB0 = Bt + (size_t)(n0 + srow) * 768 + sch;
  const u16t* gA1 = gA0 + 16 * 768;
  const u16t* gB1 = gB0 + 16 * 768;
  u16t* lb0 = smem;
  u16t* lb1 = smem + 8192;
  const int dA = w * 1024;           // (w*32 rows)*32 u16
  const int dB = 4096 + w * 1024;

  // prologue: stage K-tiles 0 and 1 (8 load insts in flight per wave)
#pragma unroll
  for (int p = 0; p < 2; ++p) {
    u16t* b = p ? lb1 : lb0;
    stage16(gA0 + p * 32, b + dA);
    stage16(gA1 + p * 32, b + dA + 512);
    stage16(gB0 + p * 32, b + dB);
    stage16(gB1 + p * 32, b + dB + 512);
  }

  // fragment slot: read G[row][ln4] -> slot = ln4 ^ ((row>>1)&3) = ln4 ^ ((ln15>>1)&3)
  const int sg = (ln4 ^ ((ln15 >> 1) & 3)) * 8;

  for (int kt = 0; kt < 24; ++kt) {
    u16t* cur = (kt & 1) ? lb1 : lb0;
    if (kt < 23) asm volatile("s_waitcnt vmcnt(4)" ::: "memory");
    else         asm volatile("s_waitcnt vmcnt(0)" ::: "memory");
    __builtin_amdgcn_s_barrier();
    __builtin_amdgcn_sched_barrier(0);   // ds_reads must not hoist above barrier
    bf16x8 af[4], bg[4];
#pragma unroll
    for (int f = 0; f < 4; ++f) {
      af[f] = *(const bf16x8*)(cur + (wr * 64 + f * 16 + ln15) * 32 + sg);
      bg[f] = *(const bf16x8*)(cur + 4096 + (wc * 64 + f * 16 + ln15) * 32 + sg);
    }
#pragma unroll
    for (int i = 0; i < 4; ++i)
#pragma unroll
      for (int j = 0; j < 4; ++j)
        acc[i][j] = __builtin_amdgcn_mfma_f32_16x16x32_bf16(af[i], bg[j], acc[i][j], 0, 0, 0);
    __builtin_amdgcn_sched_barrier(0);   // reads complete before the barrier
    __builtin_amdgcn_s_barrier();        // all waves done reading cur
    __builtin_amdgcn_sched_barrier(0);   // refill must not hoist above barrier
    if (kt < 22) {
      const int ko = (kt + 2) * 32;
      stage16(gA0 + ko, cur + dA);
      stage16(gA1 + ko, cur + dA + 512);
      stage16(gB0 + ko, cur + dB);
      stage16(gB1 + ko, cur + dB + 512);
    }
  }

  const int mq = m0 + wr * 64;
  if (mq < ropeRows) {
#pragma unroll
    for (int j4 = 0; j4 < 4; ++j4)
#pragma unroll
      for (int nf = 0; nf < 4; ++nf) {
        int n = n0 + wc * 64 + nf * 16 + ln15;
#pragma unroll
        for (int p = 0; p < 2; ++p) {
          int fidx = p * 16 + ln4 * 4 + j4;
          float cc = cosT[fidx * S_LEN + n], ss = sinT[fidx * S_LEN + n];
          float lo = acc[p][nf][j4], hi = acc[p + 2][nf][j4];
          acc[p][nf][j4]     = lo * cc - hi * ss;
          acc[p + 2][nf][j4] = hi * cc + lo * ss;
        }
      }
  }

  if (MODE == 1 && m0 < 1536) {
    __syncthreads();
    // transposed store: Cs_T[n][m], stride 136 u16 (16B-aligned rows)
    u16t* Cs = smem;
#pragma unroll
    for (int i = 0; i < 4; ++i)
#pragma unroll
      for (int nf = 0; nf < 4; ++nf) {
        int n_l = wc * 64 + nf * 16 + ln15;
        int m_l = wr * 64 + i * 16 + ln4 * 4;
        union { u16t h[4]; uint2 u2; } pk;
#pragma unroll
        for (int j4 = 0; j4 < 4; ++j4) pk.h[j4] = f2bf_u16(acc[i][nf][j4]);
        *(uint2*)(Cs + n_l * 136 + m_l) = pk.u2;
      }
    __syncthreads();
    u16t* Co = (u16t*)C1;   // qkT [4096][1536]
#pragma unroll
    for (int it = 0; it < 8; ++it) {
      int idx = it * 256 + t;
      int row = idx >> 4, ch = idx & 15;
      *(uint4*)&Co[(size_t)(n0 + row) * 1536 + m0 + ch * 8] =
          *(const uint4*)&Cs[row * 136 + ch * 8];
    }
  } else if (MODE == 1) {
    __syncthreads();
    // natural bf16 store into vbuf [768][4096]
    u16t* Cs = smem;
#pragma unroll
    for (int i = 0; i < 4; ++i)
#pragma unroll
      for (int j4 = 0; j4 < 4; ++j4) {
        int mrow = wr * 64 + i * 16 + ln4 * 4 + j4;
#pragma unroll
        for (int nf = 0; nf < 4; ++nf) {
          int col = wc * 64 + nf * 16 + ln15;
          Cs[mrow * 128 + col] = f2bf_u16(acc[i][nf][j4]);
        }
      }
    __syncthreads();
    u16t* Co = (u16t*)C2;
#pragma unroll
    for (int it = 0; it < 8; ++it) {
      int idx = it * 256 + t;
      int row = idx >> 4, ch = idx & 15;
      *(uint4*)&Co[(size_t)(m0 - 1536 + row) * S_LEN + n0 + ch * 8] =
          *(const uint4*)&Cs[row * 128 + ch * 8];
    }
  } else {
    // MODE 0: direct f32 stores (16 lanes x 4B = 64B segments)
    float* Co = (float*)C1;
#pragma unroll
    for (int i = 0; i < 4; ++i)
#pragma unroll
      for (int j4 = 0; j4 < 4; ++j4) {
        int m = m0 + wr * 64 + i * 16 + ln4 * 4 + j4;
#pragma unroll
        for (int nf = 0; nf < 4; ++nf)
          Co[(size_t)m * S_LEN + n0 + wc * 64 + nf * 16 + ln15] = acc[i][nf][j4];
      }
  }
}

// ---------------- windowed attention via MFMA (unchanged from round 8) ----------------
__global__ __launch_bounds__(256) void attn_kernel(
    const u16t* __restrict__ qkT, const u16t* __restrict__ vbuf,
    const float* __restrict__ amask, u16t* __restrict__ attnT)
{
  __shared__ __align__(16) u16t sm[24576];   // 49152 B
  u16t* KP = sm;           // Kt rows stride 64, later P rows stride 192
  u16t* Vt = sm + 12288;   // rows stride 192

  const int t = threadIdx.x;
  const int lane = t & 63, w = t >> 6;
  const int fr = lane & 15, fc = lane >> 4;

  const int nid = (blockIdx.x & 7) * 96 + (blockIdx.x >> 3);
  const int h = nid / 64, qt = nid % 64;
  const int q0 = qt * 64;
  const int kstart = q0 - 64;

  if (q0 == 0) {
    *(uint4*)(KP + t * 8) = make_uint4(0, 0, 0, 0);
    *(uint4*)(KP + 2048 + t * 8) = make_uint4(0, 0, 0, 0);
#pragma unroll
    for (int j = 0; j < 2; ++j) {
      int unit = t + 256 * j;
      *(uint4*)(Vt + (unit >> 3) * 192 + (unit & 7) * 8) = make_uint4(0, 0, 0, 0);
    }
  } else if (q0 == S_LEN - 64) {
    *(uint4*)(KP + 8192 + t * 8) = make_uint4(0, 0, 0, 0);
    *(uint4*)(KP + 10240 + t * 8) = make_uint4(0, 0, 0, 0);
#pragma unroll
    for (int j = 0; j < 2; ++j) {
      int unit = t + 256 * j;
      *(uint4*)(Vt + (unit >> 3) * 192 + 128 + (unit & 7) * 8) = make_uint4(0, 0, 0, 0);
    }
  }

  const u16t* kcolbase = qkT + 768 + h * 64;
#pragma unroll
  for (int jj = 0; jj < 6; ++jj) {
    int ii = jj * 256 + t;
    int row = ii >> 3, ch = ii & 7;
    int key = kstart + row;
    if (key >= 0 && key < S_LEN)
      stage16(kcolbase + (size_t)key * 1536 + ((ch ^ (row & 7)) * 8),
              KP + (jj * 256 + w * 64) * 8);
  }
#pragma unroll
  for (int jj = 0; jj < 6; ++jj) {
    int ii = jj * 256 + t;
    int row = ii / 24, ch = ii - row * 24;
    int sc = (ch & 24) | ((ch & 7) ^ (row & 7));
    int kf = kstart + sc * 8;
    if (kf >= 0 && kf < S_LEN)
      stage16(vbuf + (size_t)(h * 64 + row) * S_LEN + kf,
              Vt + (jj * 256 + w * 64) * 8);
  }
  const u16t* qrow = qkT + (size_t)(q0 + w * 16 + fr) * 1536 + h * 64;
  bf16x8 qa0 = *(const bf16x8*)(qrow + fc * 8);
  bf16x8 qa1 = *(const bf16x8*)(qrow + 32 + fc * 8);

  __syncthreads();

  f32x4 acc[12];
#pragma unroll
  for (int nt = 0; nt < 12; ++nt) acc[nt] = (f32x4){0.f, 0.f, 0.f, 0.f};
  __builtin_amdgcn_s_setprio(1);
#pragma unroll
  for (int nt = 0; nt < 12; ++nt) {
    int row = nt * 16 + fr;
    bf16x8 kb0 = *(const bf16x8*)(KP + row * 64 + ((fc ^ (fr & 7)) * 8));
    acc[nt] = __builtin_amdgcn_mfma_f32_16x16x32_bf16(qa0, kb0, acc[nt], 0, 0, 0);
    bf16x8 kb1 = *(const bf16x8*)(KP + row * 64 + (((4 + fc) ^ (fr & 7)) * 8));
    acc[nt] = __builtin_amdgcn_mfma_f32_16x16x32_bf16(qa1, kb1, acc[nt], 0, 0, 0);
  }
  __builtin_amdgcn_s_setprio(0);

  float rm[4] = {-3.0e38f, -3.0e38f, -3.0e38f, -3.0e38f};
#pragma unroll
  for (int nt = 0; nt < 12; ++nt) {
    int kk = nt * 16 + fr;
    int key = kstart + kk;
#pragma unroll
    for (int r = 0; r < 4; ++r) {
      int q = w * 16 + fc * 4 + r;
      int dk = kk - q;
      bool inw = (key >= 0) && (key < S_LEN) && (dk >= 0) && (dk <= 128);
      float s = -3.0e38f;
      if (inw) s = acc[nt][r] * 0.125f + amask[(size_t)(q0 + q) * S_LEN + key];
      acc[nt][r] = s;
      rm[r] = fmaxf(rm[r], s);
    }
  }
#pragma unroll
  for (int r = 0; r < 4; ++r)
#pragma unroll
    for (int off = 1; off < 16; off <<= 1)
      rm[r] = fmaxf(rm[r], __shfl_xor(rm[r], off));

  float rs[4] = {0.f, 0.f, 0.f, 0.f};
#pragma unroll
  for (int nt = 0; nt < 12; ++nt)
#pragma unroll
    for (int r = 0; r < 4; ++r) {
      float e = __expf(acc[nt][r] - rm[r]);
      acc[nt][r] = e;
      rs[r] += e;
    }
#pragma unroll
  for (int r = 0; r < 4; ++r)
#pragma unroll
    for (int off = 1; off < 16; off <<= 1)
      rs[r] += __shfl_xor(rs[r], off);

  __syncthreads();   // all waves done reading Kt -> safe to overwrite with P

#pragma unroll
  for (int nt = 0; nt < 12; ++nt) {
    int kk = nt * 16 + fr;
    int cg = kk >> 3;
#pragma unroll
    for (int r = 0; r < 4; ++r) {
      int q = w * 16 + fc * 4 + r;
      int csw = (cg & 24) | ((cg & 7) ^ (q & 7));
      KP[q * 192 + csw * 8 + (kk & 7)] = f2bf_u16(acc[nt][r]);
    }
  }
  // no barrier: PV reads only this wave's P rows; within-wave RAW is lgkm-ordered

  f32x4 acc2[4];
#pragma unroll
  for (int nt = 0; nt < 4; ++nt) acc2[nt] = (f32x4){0.f, 0.f, 0.f, 0.f};
  __builtin_amdgcn_s_setprio(1);
#pragma unroll
  for (int c32 = 0; c32 < 6; ++c32) {
    int cg = c32 * 4 + fc;
    int csA = (cg & 24) | ((cg & 7) ^ (fr & 7));
    bf16x8 pa = *(const bf16x8*)(KP + (w * 16 + fr) * 192 + csA * 8);
#pragma unroll
    for (int nt = 0; nt < 4; ++nt) {
      int d = nt * 16 + fr;
      bf16x8 vb = *(const bf16x8*)(Vt + d * 192 + csA * 8);
      acc2[nt] = __builtin_amdgcn_mfma_f32_16x16x32_bf16(pa, vb, acc2[nt], 0, 0, 0);
    }
  }
  __builtin_amdgcn_s_setprio(0);

  float inv[4];
#pragma unroll
  for (int r = 0; r < 4; ++r) inv[r] = 1.f / rs[r];
#pragma unroll
  for (int nt = 0; nt < 4; ++nt)
#pragma unroll
    for (int r = 0; r < 4; ++r) {
      int q = w * 16 + fc * 4 + r;
      int d = nt * 16 + fr;
      attnT[(size_t)(q0 + q) * 768 + h * 64 + d] = f2bf_u16(acc2[nt][r] * inv[r]);
    }
}

extern "C" void kernel_launch(void* const* d_in, const int* in_sizes, int n_in,
                              void* d_out, int out_size, void* d_ws, size_t ws_size,
                              hipStream_t stream) {
  const float* x     = (const float*)d_in[0];
  const int*   pos   = (const int*)d_in[1];
  const float* amask = (const float*)d_in[2];
  const float* qkvw  = (const float*)d_in[3];
  const float* outw  = (const float*)d_in[4];
  float* out = (float*)d_out;

  char* ws = (char*)d_ws;
  float* cosT   = (float*)ws;                          ws += 32 * S_LEN * 4;
  float* sinT   = (float*)ws;                          ws += 32 * S_LEN * 4;
  u16t*  xT     = (u16t*)ws;                           ws += (size_t)S_LEN * 768 * 2;
  u16t*  wq_bf  = (u16t*)ws;                           ws += (size_t)2304 * 768 * 2;
  u16t*  wo_bf  = (u16t*)ws;                           ws += (size_t)768 * 768 * 2;
  u16t*  qkT    = (u16t*)ws;                           ws += (size_t)S_LEN * 1536 * 2;
  u16t*  vbuf   = (u16t*)ws;                           ws += (size_t)768 * S_LEN * 2;
  u16t*  attnT  = (u16t*)ws;

  // fused prep: tcast(768) | castw wq(1728) | castw wo(576) | rope(512)
  prep_kernel<<<3584, 256, 0, stream>>>(x, xT, qkvw, wq_bf, outw, wo_bf, pos, cosT, sinT);
  // QKV: 18x32 tiles, XCD rect = 9m x 8n
  gemm_kernel<1><<<576, 256, 0, stream>>>(wq_bf, xT, qkT, vbuf, cosT, sinT, 1536, 32, 8, 9);
  attn_kernel<<<768, 256, 0, stream>>>(qkT, vbuf, amask, attnT);
  // out-proj: 6x32 tiles, XCD rect = 6m x 4n
  gemm_kernel<0><<<192, 256, 0, stream>>>(wo_bf, attnT, out, nullptr, cosT, sinT, 0, 32, 4, 6);
}

// Round 11
// 65.565 us; speedup vs baseline: 1.8776x; 1.0998x over previous
//
#include <hip/hip_runtime.h>
#include <hip/hip_bf16.h>
#include <math.h>

#define S_LEN 4096

typedef unsigned short u16t;
typedef unsigned int u32t;
typedef __attribute__((ext_vector_type(4))) short bf16x4;
typedef __attribute__((ext_vector_type(8))) short bf16x8;
typedef __attribute__((ext_vector_type(4))) float f32x4;

__device__ __forceinline__ u16t f2bf_u16(float f) {
  union { __hip_bfloat16 h; u16t u; } r; r.h = __float2bfloat16(f); return r.u;
}

// async global->LDS, 16B per lane; LDS dest = wave-uniform base + lane*16
__device__ __forceinline__ void stage16(const u16t* g, u16t* l) {
  __builtin_amdgcn_global_load_lds(
      (const __attribute__((address_space(1))) void*)g,
      (__attribute__((address_space(3))) void*)l, 16, 0, 0);
}

// ---------------- fused prep: tcast | castw(wq) | castw(wo) | rope ----------------
__global__ __launch_bounds__(256) void prep_kernel(
    const float* __restrict__ x, u16t* __restrict__ xT,
    const float* __restrict__ qkvw, u16t* __restrict__ wq,
    const float* __restrict__ outw, u16t* __restrict__ wo,
    const int* __restrict__ pos, float* __restrict__ cosT, float* __restrict__ sinT)
{
  __shared__ float T[64][65];
  const int b = blockIdx.x;
  const int t = threadIdx.x;
  if (b < 768) {
    int s0 = (b & 63) * 64, c0 = (b >> 6) * 64;
    int sl = t & 63, g = t >> 6;
#pragma unroll
    for (int r = 0; r < 16; ++r) {
      int cl = g + 4 * r;
      T[cl][sl] = x[(size_t)(c0 + cl) * S_LEN + s0 + sl];
    }
    __syncthreads();
#pragma unroll
    for (int r = 0; r < 16; ++r) {
      int sl2 = g + 4 * r;
      xT[(size_t)(s0 + sl2) * 768 + c0 + sl] = f2bf_u16(T[sl][sl2]);
    }
  } else if (b < 3072) {
    const float* src; u16t* dst; int i;
    if (b < 2496) { src = qkvw; dst = wq; i = (b - 768) * 256 + t; }
    else          { src = outw; dst = wo; i = (b - 2496) * 256 + t; }
    float4 v = ((const float4*)src)[i];
    union { u16t h[4]; uint2 u; } r;
    r.h[0] = f2bf_u16(v.x); r.h[1] = f2bf_u16(v.y);
    r.h[2] = f2bf_u16(v.z); r.h[3] = f2bf_u16(v.w);
    ((uint2*)dst)[i] = r.u;
  } else {
    int idx = (b - 3072) * 256 + t;
    int j = idx >> 12, s = idx & 4095;
    double p = (double)pos[s];
    double inv = exp(-((double)(2 * j) / 64.0) * log(10000.0));
    double a = p * inv;
    cosT[idx] = (float)cos(a);
    sinT[idx] = (float)sin(a);
  }
}

// ---------------- bf16 MFMA GEMM, 128x128 tile, BK=32, 3-deep, 3 blocks/CU ----
// Counted-vmcnt triple-buffer: prologue stages K-tiles 0,1,2 (12 loads);
// per iter: vmcnt(8) -> barrier -> PIN -> 16 MFMA -> PIN -> barrier -> PIN ->
// refill(kt+3 into the buffer just read). Drain 8->4->0 over last 3 iters.
// sched_barrier(0) pins REQUIRED (raw s_barrier has no compiler memory
// semantics; round-9 failure). LDS 48KB static (epilogue overlays) -> 3/CU.
// MODE 0: C f32 natural [M][4096] -> C1 (direct coalesced stores)
// MODE 1: m0<1536 -> C^T bf16 into qkT [4096][1536] (C1); else V natural bf16
//         into vbuf [768][4096] (C2). RoPE epilogue for m < ropeRows.
template <int MODE>
__global__ __launch_bounds__(256, 3) void gemm_kernel(
    const u16t* __restrict__ A, const u16t* __restrict__ Bt,
    void* __restrict__ C1, void* __restrict__ C2,
    const float* __restrict__ cosT, const float* __restrict__ sinT, int ropeRows,
    int tilesX, int rectW, int rectH)
{
  __shared__ __align__(16) u16t smem[24576];   // 3 x 16KB buffers; epilogue reuses
  const int t = threadIdx.x;
  const int lane = t & 63, w = t >> 6;
  const int wr = w >> 1, wc = w & 1;
  const int ln15 = lane & 15, ln4 = lane >> 4;

  // rectangle XCD mapping (grid must be multiple of 8)
  const int xcd = blockIdx.x & 7;
  const int local = blockIdx.x >> 3;
  const int nrectX = tilesX / rectW;
  const int lm = local / rectW, ln = local - lm * rectW;
  const int m0 = ((xcd / nrectX) * rectH + lm) * 128;
  const int n0 = ((xcd % nrectX) * rectW + ln) * 128;

  f32x4 acc[4][4];
#pragma unroll
  for (int i = 0; i < 4; ++i)
#pragma unroll
    for (int j = 0; j < 4; ++j) acc[i][j] = (f32x4){0.f, 0.f, 0.f, 0.f};

  // staging: thread covers rows w*32+(lane>>2) and +16; slot = lane&3.
  // LDS[row][slot] = G[row][slot ^ ((row>>1)&3)]; (row>>1)&3 == (lane>>3)&3.
  const int srow = w * 32 + (lane >> 2);
  const int sch  = ((lane & 3) ^ ((lane >> 3) & 3)) * 8;
  const u16t* gA0 = A  + (size_t)(m0 + srow) * 768 + sch;
  const u16t* gB0 = Bt + (size_t)(n0 + srow) * 768 + sch;
  const u16t* gA1 = gA0 + 16 * 768;
  const u16t* gB1 = gB0 + 16 * 768;
  const int dA = w * 1024;           // (w*32 rows)*32 u16
  const int dB = 4096 + w * 1024;

  // prologue: stage K-tiles 0,1,2 (12 load insts in flight per wave)
#pragma unroll
  for (int p = 0; p < 3; ++p) {
    u16t* b = smem + p * 8192;
    stage16(gA0 + p * 32, b + dA);
    stage16(gA1 + p * 32, b + dA + 512);
    stage16(gB0 + p * 32, b + dB);
    stage16(gB1 + p * 32, b + dB + 512);
  }

  // fragment slot: read G[row][ln4] -> slot = ln4 ^ ((row>>1)&3) = ln4 ^ ((ln15>>1)&3)
  const int sg = (ln4 ^ ((ln15 >> 1) & 3)) * 8;

  int bufsel = 0;
  for (int kt = 0; kt < 24; ++kt) {
    u16t* cur = smem + bufsel * 8192;
    bufsel = (bufsel == 2) ? 0 : bufsel + 1;
    if (kt < 22)       asm volatile("s_waitcnt vmcnt(8)" ::: "memory");
    else if (kt == 22) asm volatile("s_waitcnt vmcnt(4)" ::: "memory");
    else               asm volatile("s_waitcnt vmcnt(0)" ::: "memory");
    __builtin_amdgcn_s_barrier();
    __builtin_amdgcn_sched_barrier(0);   // ds_reads must not hoist above barrier
    bf16x8 af[4], bg[4];
#pragma unroll
    for (int f = 0; f < 4; ++f) {
      af[f] = *(const bf16x8*)(cur + (wr * 64 + f * 16 + ln15) * 32 + sg);
      bg[f] = *(const bf16x8*)(cur + 4096 + (wc * 64 + f * 16 + ln15) * 32 + sg);
    }
#pragma unroll
    for (int i = 0; i < 4; ++i)
#pragma unroll
      for (int j = 0; j < 4; ++j)
        acc[i][j] = __builtin_amdgcn_mfma_f32_16x16x32_bf16(af[i], bg[j], acc[i][j], 0, 0, 0);
    __builtin_amdgcn_sched_barrier(0);   // reads complete before the barrier
    __builtin_amdgcn_s_barrier();        // all waves done reading cur
    __builtin_amdgcn_sched_barrier(0);   // refill must not hoist above barrier
    if (kt < 21) {
      const int ko = (kt + 3) * 32;
      stage16(gA0 + ko, cur + dA);
      stage16(gA1 + ko, cur + dA + 512);
      stage16(gB0 + ko, cur + dB);
      stage16(gB1 + ko, cur + dB + 512);
    }
  }

  const int mq = m0 + wr * 64;
  if (mq < ropeRows) {
#pragma unroll
    for (int j4 = 0; j4 < 4; ++j4)
#pragma unroll
      for (int nf = 0; nf < 4; ++nf) {
        int n = n0 + wc * 64 + nf * 16 + ln15;
#pragma unroll
        for (int p = 0; p < 2; ++p) {
          int fidx = p * 16 + ln4 * 4 + j4;
          float cc = cosT[fidx * S_LEN + n], ss = sinT[fidx * S_LEN + n];
          float lo = acc[p][nf][j4], hi = acc[p + 2][nf][j4];
          acc[p][nf][j4]     = lo * cc - hi * ss;
          acc[p + 2][nf][j4] = hi * cc + lo * ss;
        }
      }
  }

  if (MODE == 1 && m0 < 1536) {
    __syncthreads();
    // transposed store: Cs_T[n][m], stride 136 u16 (16B-aligned rows)
    u16t* Cs = smem;
#pragma unroll
    for (int i = 0; i < 4; ++i)
#pragma unroll
      for (int nf = 0; nf < 4; ++nf) {
        int n_l = wc * 64 + nf * 16 + ln15;
        int m_l = wr * 64 + i * 16 + ln4 * 4;
        union { u16t h[4]; uint2 u2; } pk;
#pragma unroll
        for (int j4 = 0; j4 < 4; ++j4) pk.h[j4] = f2bf_u16(acc[i][nf][j4]);
        *(uint2*)(Cs + n_l * 136 + m_l) = pk.u2;
      }
    __syncthreads();
    u16t* Co = (u16t*)C1;   // qkT [4096][1536]
#pragma unroll
    for (int it = 0; it < 8; ++it) {
      int idx = it * 256 + t;
      int row = idx >> 4, ch = idx & 15;
      *(uint4*)&Co[(size_t)(n0 + row) * 1536 + m0 + ch * 8] =
          *(const uint4*)&Cs[row * 136 + ch * 8];
    }
  } else if (MODE == 1) {
    __syncthreads();
    // natural bf16 store into vbuf [768][4096]
    u16t* Cs = smem;
#pragma unroll
    for (int i = 0; i < 4; ++i)
#pragma unroll
      for (int j4 = 0; j4 < 4; ++j4) {
        int mrow = wr * 64 + i * 16 + ln4 * 4 + j4;
#pragma unroll
        for (int nf = 0; nf < 4; ++nf) {
          int col = wc * 64 + nf * 16 + ln15;
          Cs[mrow * 128 + col] = f2bf_u16(acc[i][nf][j4]);
        }
      }
    __syncthreads();
    u16t* Co = (u16t*)C2;
#pragma unroll
    for (int it = 0; it < 8; ++it) {
      int idx = it * 256 + t;
      int row = idx >> 4, ch = idx & 15;
      *(uint4*)&Co[(size_t)(m0 - 1536 + row) * S_LEN + n0 + ch * 8] =
          *(const uint4*)&Cs[row * 128 + ch * 8];
    }
  } else {
    // MODE 0: direct f32 stores (16 lanes x 4B = 64B segments)
    float* Co = (float*)C1;
#pragma unroll
    for (int i = 0; i < 4; ++i)
#pragma unroll
      for (int j4 = 0; j4 < 4; ++j4) {
        int m = m0 + wr * 64 + i * 16 + ln4 * 4 + j4;
#pragma unroll
        for (int nf = 0; nf < 4; ++nf)
          Co[(size_t)m * S_LEN + n0 + wc * 64 + nf * 16 + ln15] = acc[i][nf][j4];
      }
  }
}

// ---------------- windowed attention via MFMA ----------------
// round-10 structure + amask loads hoisted above the barrier (issue-early):
// 48 loads ride the staging latency instead of exposing HBM/L3 latency
// between QK^T and softmax. Cols clamped; in-window guard discards junk.
__global__ __launch_bounds__(256, 3) void attn_kernel(
    const u16t* __restrict__ qkT, const u16t* __restrict__ vbuf,
    const float* __restrict__ amask, u16t* __restrict__ attnT)
{
  __shared__ __align__(16) u16t sm[24576];   // 49152 B
  u16t* KP = sm;           // Kt rows stride 64, later P rows stride 192
  u16t* Vt = sm + 12288;   // rows stride 192

  const int t = threadIdx.x;
  const int lane = t & 63, w = t >> 6;
  const int fr = lane & 15, fc = lane >> 4;

  const int nid = (blockIdx.x & 7) * 96 + (blockIdx.x >> 3);
  const int h = nid / 64, qt = nid % 64;
  const int q0 = qt * 64;
  const int kstart = q0 - 64;

  if (q0 == 0) {
    *(uint4*)(KP + t * 8) = make_uint4(0, 0, 0, 0);
    *(uint4*)(KP + 2048 + t * 8) = make_uint4(0, 0, 0, 0);
#pragma unroll
    for (int j = 0; j < 2; ++j) {
      int unit = t + 256 * j;
      *(uint4*)(Vt + (unit >> 3) * 192 + (unit & 7) * 8) = make_uint4(0, 0, 0, 0);
    }
  } else if (q0 == S_LEN - 64) {
    *(uint4*)(KP + 8192 + t * 8) = make_uint4(0, 0, 0, 0);
    *(uint4*)(KP + 10240 + t * 8) = make_uint4(0, 0, 0, 0);
#pragma unroll
    for (int j = 0; j < 2; ++j) {
      int unit = t + 256 * j;
      *(uint4*)(Vt + (unit >> 3) * 192 + 128 + (unit & 7) * 8) = make_uint4(0, 0, 0, 0);
    }
  }

  const u16t* kcolbase = qkT + 768 + h * 64;
#pragma unroll
  for (int jj = 0; jj < 6; ++jj) {
    int ii = jj * 256 + t;
    int row = ii >> 3, ch = ii & 7;
    int key = kstart + row;
    if (key >= 0 && key < S_LEN)
      stage16(kcolbase + (size_t)key * 1536 + ((ch ^ (row & 7)) * 8),
              KP + (jj * 256 + w * 64) * 8);
  }
#pragma unroll
  for (int jj = 0; jj < 6; ++jj) {
    int ii = jj * 256 + t;
    int row = ii / 24, ch = ii - row * 24;
    int sc = (ch & 24) | ((ch & 7) ^ (row & 7));
    int kf = kstart + sc * 8;
    if (kf >= 0 && kf < S_LEN)
      stage16(vbuf + (size_t)(h * 64 + row) * S_LEN + kf,
              Vt + (jj * 256 + w * 64) * 8);
  }
  const u16t* qrow = qkT + (size_t)(q0 + w * 16 + fr) * 1536 + h * 64;
  bf16x8 qa0 = *(const bf16x8*)(qrow + fc * 8);
  bf16x8 qa1 = *(const bf16x8*)(qrow + 32 + fc * 8);

  // amask hoist: issue all 48 loads now; they complete by the barrier below
  float am[12][4];
  const int qb = q0 + w * 16 + fc * 4;
#pragma unroll
  for (int nt = 0; nt < 12; ++nt) {
    int key = kstart + nt * 16 + fr;
    int keyc = min(max(key, 0), S_LEN - 1);
#pragma unroll
    for (int r = 0; r < 4; ++r)
      am[nt][r] = amask[(size_t)(qb + r) * S_LEN + keyc];
  }

  __syncthreads();

  f32x4 acc[12];
#pragma unroll
  for (int nt = 0; nt < 12; ++nt) acc[nt] = (f32x4){0.f, 0.f, 0.f, 0.f};
  __builtin_amdgcn_s_setprio(1);
#pragma unroll
  for (int nt = 0; nt < 12; ++nt) {
    int row = nt * 16 + fr;
    bf16x8 kb0 = *(const bf16x8*)(KP + row * 64 + ((fc ^ (fr & 7)) * 8));
    acc[nt] = __builtin_amdgcn_mfma_f32_16x16x32_bf16(qa0, kb0, acc[nt], 0, 0, 0);
    bf16x8 kb1 = *(const bf16x8*)(KP + row * 64 + (((4 + fc) ^ (fr & 7)) * 8));
    acc[nt] = __builtin_amdgcn_mfma_f32_16x16x32_bf16(qa1, kb1, acc[nt], 0, 0, 0);
  }
  __builtin_amdgcn_s_setprio(0);

  float rm[4] = {-3.0e38f, -3.0e38f, -3.0e38f, -3.0e38f};
#pragma unroll
  for (int nt = 0; nt < 12; ++nt) {
    int kk = nt * 16 + fr;
    int key = kstart + kk;
#pragma unroll
    for (int r = 0; r < 4; ++r) {
      int q = w * 16 + fc * 4 + r;
      int dk = kk - q;
      bool inw = (key >= 0) && (key < S_LEN) && (dk >= 0) && (dk <= 128);
      float s = -3.0e38f;
      if (inw) s = acc[nt][r] * 0.125f + am[nt][r];
      acc[nt][r] = s;
      rm[r] = fmaxf(rm[r], s);
    }
  }
#pragma unroll
  for (int r = 0; r < 4; ++r)
#pragma unroll
    for (int off = 1; off < 16; off <<= 1)
      rm[r] = fmaxf(rm[r], __shfl_xor(rm[r], off));

  float rs[4] = {0.f, 0.f, 0.f, 0.f};
#pragma unroll
  for (int nt = 0; nt < 12; ++nt)
#pragma unroll
    for (int r = 0; r < 4; ++r) {
      float e = __expf(acc[nt][r] - rm[r]);
      acc[nt][r] = e;
      rs[r] += e;
    }
#pragma unroll
  for (int r = 0; r < 4; ++r)
#pragma unroll
    for (int off = 1; off < 16; off <<= 1)
      rs[r] += __shfl_xor(rs[r], off);

  __syncthreads();   // all waves done reading Kt -> safe to overwrite with P

#pragma unroll
  for (int nt = 0; nt < 12; ++nt) {
    int kk = nt * 16 + fr;
    int cg = kk >> 3;
#pragma unroll
    for (int r = 0; r < 4; ++r) {
      int q = w * 16 + fc * 4 + r;
      int csw = (cg & 24) | ((cg & 7) ^ (q & 7));
      KP[q * 192 + csw * 8 + (kk & 7)] = f2bf_u16(acc[nt][r]);
    }
  }
  // no barrier: PV reads only this wave's P rows; within-wave RAW is lgkm-ordered

  f32x4 acc2[4];
#pragma unroll
  for (int nt = 0; nt < 4; ++nt) acc2[nt] = (f32x4){0.f, 0.f, 0.f, 0.f};
  __builtin_amdgcn_s_setprio(1);
#pragma unroll
  for (int c32 = 0; c32 < 6; ++c32) {
    int cg = c32 * 4 + fc;
    int csA = (cg & 24) | ((cg & 7) ^ (fr & 7));
    bf16x8 pa = *(const bf16x8*)(KP + (w * 16 + fr) * 192 + csA * 8);
#pragma unroll
    for (int nt = 0; nt < 4; ++nt) {
      int d = nt * 16 + fr;
      bf16x8 vb = *(const bf16x8*)(Vt + d * 192 + csA * 8);
      acc2[nt] = __builtin_amdgcn_mfma_f32_16x16x32_bf16(pa, vb, acc2[nt], 0, 0, 0);
    }
  }
  __builtin_amdgcn_s_setprio(0);

  float inv[4];
#pragma unroll
  for (int r = 0; r < 4; ++r) inv[r] = 1.f / rs[r];
#pragma unroll
  for (int nt = 0; nt < 4; ++nt)
#pragma unroll
    for (int r = 0; r < 4; ++r) {
      int q = w * 16 + fc * 4 + r;
      int d = nt * 16 + fr;
      attnT[(size_t)(q0 + q) * 768 + h * 64 + d] = f2bf_u16(acc2[nt][r] * inv[r]);
    }
}

extern "C" void kernel_launch(void* const* d_in, const int* in_sizes, int n_in,
                              void* d_out, int out_size, void* d_ws, size_t ws_size,
                              hipStream_t stream) {
  const float* x     = (const float*)d_in[0];
  const int*   pos   = (const int*)d_in[1];
  const float* amask = (const float*)d_in[2];
  const float* qkvw  = (const float*)d_in[3];
  const float* outw  = (const float*)d_in[4];
  float* out = (float*)d_out;

  char* ws = (char*)d_ws;
  float* cosT   = (float*)ws;                          ws += 32 * S_LEN * 4;
  float* sinT   = (float*)ws;                          ws += 32 * S_LEN * 4;
  u16t*  xT     = (u16t*)ws;                           ws += (size_t)S_LEN * 768 * 2;
  u16t*  wq_bf  = (u16t*)ws;                           ws += (size_t)2304 * 768 * 2;
  u16t*  wo_bf  = (u16t*)ws;                           ws += (size_t)768 * 768 * 2;
  u16t*  qkT    = (u16t*)ws;                           ws += (size_t)S_LEN * 1536 * 2;
  u16t*  vbuf   = (u16t*)ws;                           ws += (size_t)768 * S_LEN * 2;
  u16t*  attnT  = (u16t*)ws;

  // fused prep: tcast(768) | castw wq(1728) | castw wo(576) | rope(512)
  prep_kernel<<<3584, 256, 0, stream>>>(x, xT, qkvw, wq_bf, outw, wo_bf, pos, cosT, sinT);
  // QKV: 18x32 tiles, XCD rect = 9m x 8n
  gemm_kernel<1><<<576, 256, 0, stream>>>(wq_bf, xT, qkT, vbuf, cosT, sinT, 1536, 32, 8, 9);
  attn_kernel<<<768, 256, 0, stream>>>(qkT, vbuf, amask, attnT);
  // out-proj: 6x32 tiles, XCD rect = 6m x 4n
  gemm_kernel<0><<<192, 256, 0, stream>>>(wo_bf, attnT, out, nullptr, cosT, sinT, 0, 32, 4, 6);
}

// Round 12
// 63.332 us; speedup vs baseline: 1.9438x; 1.0352x over previous
//
#include <hip/hip_runtime.h>
#include <hip/hip_bf16.h>
#include <math.h>

#define S_LEN 4096

typedef unsigned short u16t;
typedef unsigned int u32t;
typedef __attribute__((ext_vector_type(4))) short bf16x4;
typedef __attribute__((ext_vector_type(8))) short bf16x8;
typedef __attribute__((ext_vector_type(4))) float f32x4;

__device__ __forceinline__ u16t f2bf_u16(float f) {
  union { __hip_bfloat16 h; u16t u; } r; r.h = __float2bfloat16(f); return r.u;
}

// async global->LDS, 16B per lane; LDS dest = wave-uniform base + lane*16
__device__ __forceinline__ void stage16(const u16t* g, u16t* l) {
  __builtin_amdgcn_global_load_lds(
      (const __attribute__((address_space(1))) void*)g,
      (__attribute__((address_space(3))) void*)l, 16, 0, 0);
}

// ---------------- fused prep: tcast | castw(wq) | castw(wo) | rope ----------------
__global__ __launch_bounds__(256) void prep_kernel(
    const float* __restrict__ x, u16t* __restrict__ xT,
    const float* __restrict__ qkvw, u16t* __restrict__ wq,
    const float* __restrict__ outw, u16t* __restrict__ wo,
    const int* __restrict__ pos, float* __restrict__ cosT, float* __restrict__ sinT)
{
  __shared__ float T[64][65];
  const int b = blockIdx.x;
  const int t = threadIdx.x;
  if (b < 768) {
    int s0 = (b & 63) * 64, c0 = (b >> 6) * 64;
    int sl = t & 63, g = t >> 6;
#pragma unroll
    for (int r = 0; r < 16; ++r) {
      int cl = g + 4 * r;
      T[cl][sl] = x[(size_t)(c0 + cl) * S_LEN + s0 + sl];
    }
    __syncthreads();
#pragma unroll
    for (int r = 0; r < 16; ++r) {
      int sl2 = g + 4 * r;
      xT[(size_t)(s0 + sl2) * 768 + c0 + sl] = f2bf_u16(T[sl][sl2]);
    }
  } else if (b < 3072) {
    const float* src; u16t* dst; int i;
    if (b < 2496) { src = qkvw; dst = wq; i = (b - 768) * 256 + t; }
    else          { src = outw; dst = wo; i = (b - 2496) * 256 + t; }
    float4 v = ((const float4*)src)[i];
    union { u16t h[4]; uint2 u; } r;
    r.h[0] = f2bf_u16(v.x); r.h[1] = f2bf_u16(v.y);
    r.h[2] = f2bf_u16(v.z); r.h[3] = f2bf_u16(v.w);
    ((uint2*)dst)[i] = r.u;
  } else {
    int idx = (b - 3072) * 256 + t;
    int j = idx >> 12, s = idx & 4095;
    double p = (double)pos[s];
    double inv = exp(-((double)(2 * j) / 64.0) * log(10000.0));
    double a = p * inv;
    cosT[idx] = (float)cos(a);
    sinT[idx] = (float)sin(a);
  }
}

// ---------------- bf16 MFMA GEMM, 128x128 tile, BK=32, dual-tile phases ----
// 3 rotating 16KB buffers; phase p consumes tiles 2p,2p+1 (bufs (2p)%3,(2p+1)%3),
// tile 2p+2 stays in flight (vmcnt(4) steady), refill 2p+3,2p+4 into the two
// just-read bufs. 12 phases => half the barriers of the 24-step loop, 32 MFMA
// + 16 ds_reads per pinned region. sched_barrier(0) pins REQUIRED (raw
// s_barrier has no compiler memory semantics; round-9 failure). LDS 48 KB,
// VGPR capped by launch_bounds => 3 blocks/CU.
// MODE 0: C f32 natural [M][4096] -> C1 (direct coalesced stores)
// MODE 1: m0<1536 -> C^T bf16 into qkT [4096][1536] (C1); else V natural bf16
//         into vbuf [768][4096] (C2). RoPE epilogue for m < ropeRows.
template <int MODE>
__global__ __launch_bounds__(256, 3) void gemm_kernel(
    const u16t* __restrict__ A, const u16t* __restrict__ Bt,
    void* __restrict__ C1, void* __restrict__ C2,
    const float* __restrict__ cosT, const float* __restrict__ sinT, int ropeRows,
    int tilesX, int rectW, int rectH)
{
  __shared__ __align__(16) u16t smem[24576];   // 3 x 16KB buffers; epilogue reuses
  const int t = threadIdx.x;
  const int lane = t & 63, w = t >> 6;
  const int wr = w >> 1, wc = w & 1;
  const int ln15 = lane & 15, ln4 = lane >> 4;

  // rectangle XCD mapping (grid must be multiple of 8)
  const int xcd = blockIdx.x & 7;
  const int local = blockIdx.x >> 3;
  const int nrectX = tilesX / rectW;
  const int lm = local / rectW, ln = local - lm * rectW;
  const int m0 = ((xcd / nrectX) * rectH + lm) * 128;
  const int n0 = ((xcd % nrectX) * rectW + ln) * 128;

  f32x4 acc[4][4];
#pragma unroll
  for (int i = 0; i < 4; ++i)
#pragma unroll
    for (int j = 0; j < 4; ++j) acc[i][j] = (f32x4){0.f, 0.f, 0.f, 0.f};

  // staging: thread covers rows w*32+(lane>>2) and +16; slot = lane&3.
  // LDS[row][slot] = G[row][slot ^ ((row>>1)&3)]; (row>>1)&3 == (lane>>3)&3.
  const int srow = w * 32 + (lane >> 2);
  const int sch  = ((lane & 3) ^ ((lane >> 3) & 3)) * 8;
  const u16t* gA0 = A  + (size_t)(m0 + srow) * 768 + sch;
  const u16t* gB0 = Bt + (size_t)(n0 + srow) * 768 + sch;
  const u16t* gA1 = gA0 + 16 * 768;
  const u16t* gB1 = gB0 + 16 * 768;
  const int dA = w * 1024;           // (w*32 rows)*32 u16
  const int dB = 4096 + w * 1024;

  // prologue: stage K-tiles 0,1,2 (12 load insts in flight per wave)
#pragma unroll
  for (int p = 0; p < 3; ++p) {
    u16t* b = smem + p * 8192;
    stage16(gA0 + p * 32, b + dA);
    stage16(gA1 + p * 32, b + dA + 512);
    stage16(gB0 + p * 32, b + dB);
    stage16(gB1 + p * 32, b + dB + 512);
  }

  // fragment slot: read G[row][ln4] -> slot = ln4 ^ ((row>>1)&3) = ln4 ^ ((ln15>>1)&3)
  const int sg = (ln4 ^ ((ln15 >> 1) & 3)) * 8;

#pragma unroll
  for (int ph = 0; ph < 12; ++ph) {
    const int b0 = (2 * ph) % 3;
    const int b1 = (2 * ph + 1) % 3;
    u16t* c0 = smem + b0 * 8192;
    u16t* c1 = smem + b1 * 8192;
    if (ph < 11) asm volatile("s_waitcnt vmcnt(4)" ::: "memory");
    else         asm volatile("s_waitcnt vmcnt(0)" ::: "memory");
    __builtin_amdgcn_s_barrier();
    __builtin_amdgcn_sched_barrier(0);   // ds_reads must not hoist above barrier
    {
      bf16x8 af[4], bg[4];
#pragma unroll
      for (int f = 0; f < 4; ++f) {
        af[f] = *(const bf16x8*)(c0 + (wr * 64 + f * 16 + ln15) * 32 + sg);
        bg[f] = *(const bf16x8*)(c0 + 4096 + (wc * 64 + f * 16 + ln15) * 32 + sg);
      }
#pragma unroll
      for (int i = 0; i < 4; ++i)
#pragma unroll
        for (int j = 0; j < 4; ++j)
          acc[i][j] = __builtin_amdgcn_mfma_f32_16x16x32_bf16(af[i], bg[j], acc[i][j], 0, 0, 0);
#pragma unroll
      for (int f = 0; f < 4; ++f) {
        af[f] = *(const bf16x8*)(c1 + (wr * 64 + f * 16 + ln15) * 32 + sg);
        bg[f] = *(const bf16x8*)(c1 + 4096 + (wc * 64 + f * 16 + ln15) * 32 + sg);
      }
#pragma unroll
      for (int i = 0; i < 4; ++i)
#pragma unroll
        for (int j = 0; j < 4; ++j)
          acc[i][j] = __builtin_amdgcn_mfma_f32_16x16x32_bf16(af[i], bg[j], acc[i][j], 0, 0, 0);
    }
    __builtin_amdgcn_sched_barrier(0);   // reads complete before the barrier
    __builtin_amdgcn_s_barrier();        // all waves done reading c0/c1
    __builtin_amdgcn_sched_barrier(0);   // refill must not hoist above barrier
    if (ph <= 9) {
      const int ko3 = (2 * ph + 3) * 32;   // -> buf b0
      const int ko4 = (2 * ph + 4) * 32;   // -> buf b1
      stage16(gA0 + ko3, c0 + dA);
      stage16(gA1 + ko3, c0 + dA + 512);
      stage16(gB0 + ko3, c0 + dB);
      stage16(gB1 + ko3, c0 + dB + 512);
      stage16(gA0 + ko4, c1 + dA);
      stage16(gA1 + ko4, c1 + dA + 512);
      stage16(gB0 + ko4, c1 + dB);
      stage16(gB1 + ko4, c1 + dB + 512);
    } else if (ph == 10) {
      const int ko3 = 23 * 32;             // tile 23 -> buf b0 (23%3 == b0)
      stage16(gA0 + ko3, c0 + dA);
      stage16(gA1 + ko3, c0 + dA + 512);
      stage16(gB0 + ko3, c0 + dB);
      stage16(gB1 + ko3, c0 + dB + 512);
    }
  }

  const int mq = m0 + wr * 64;
  if (mq < ropeRows) {
#pragma unroll
    for (int j4 = 0; j4 < 4; ++j4)
#pragma unroll
      for (int nf = 0; nf < 4; ++nf) {
        int n = n0 + wc * 64 + nf * 16 + ln15;
#pragma unroll
        for (int p = 0; p < 2; ++p) {
          int fidx = p * 16 + ln4 * 4 + j4;
          float cc = cosT[fidx * S_LEN + n], ss = sinT[fidx * S_LEN + n];
          float lo = acc[p][nf][j4], hi = acc[p + 2][nf][j4];
          acc[p][nf][j4]     = lo * cc - hi * ss;
          acc[p + 2][nf][j4] = hi * cc + lo * ss;
        }
      }
  }

  if (MODE == 1 && m0 < 1536) {
    __syncthreads();
    // transposed store: Cs_T[n][m], stride 136 u16 (16B-aligned rows)
    u16t* Cs = smem;
#pragma unroll
    for (int i = 0; i < 4; ++i)
#pragma unroll
      for (int nf = 0; nf < 4; ++nf) {
        int n_l = wc * 64 + nf * 16 + ln15;
        int m_l = wr * 64 + i * 16 + ln4 * 4;
        union { u16t h[4]; uint2 u2; } pk;
#pragma unroll
        for (int j4 = 0; j4 < 4; ++j4) pk.h[j4] = f2bf_u16(acc[i][nf][j4]);
        *(uint2*)(Cs + n_l * 136 + m_l) = pk.u2;
      }
    __syncthreads();
    u16t* Co = (u16t*)C1;   // qkT [4096][1536]
#pragma unroll
    for (int it = 0; it < 8; ++it) {
      int idx = it * 256 + t;
      int row = idx >> 4, ch = idx & 15;
      *(uint4*)&Co[(size_t)(n0 + row) * 1536 + m0 + ch * 8] =
          *(const uint4*)&Cs[row * 136 + ch * 8];
    }
  } else if (MODE == 1) {
    __syncthreads();
    // natural bf16 store into vbuf [768][4096]
    u16t* Cs = smem;
#pragma unroll
    for (int i = 0; i < 4; ++i)
#pragma unroll
      for (int j4 = 0; j4 < 4; ++j4) {
        int mrow = wr * 64 + i * 16 + ln4 * 4 + j4;
#pragma unroll
        for (int nf = 0; nf < 4; ++nf) {
          int col = wc * 64 + nf * 16 + ln15;
          Cs[mrow * 128 + col] = f2bf_u16(acc[i][nf][j4]);
        }
      }
    __syncthreads();
    u16t* Co = (u16t*)C2;
#pragma unroll
    for (int it = 0; it < 8; ++it) {
      int idx = it * 256 + t;
      int row = idx >> 4, ch = idx & 15;
      *(uint4*)&Co[(size_t)(m0 - 1536 + row) * S_LEN + n0 + ch * 8] =
          *(const uint4*)&Cs[row * 128 + ch * 8];
    }
  } else {
    // MODE 0: direct f32 stores (16 lanes x 4B = 64B segments)
    float* Co = (float*)C1;
#pragma unroll
    for (int i = 0; i < 4; ++i)
#pragma unroll
      for (int j4 = 0; j4 < 4; ++j4) {
        int m = m0 + wr * 64 + i * 16 + ln4 * 4 + j4;
#pragma unroll
        for (int nf = 0; nf < 4; ++nf)
          Co[(size_t)m * S_LEN + n0 + wc * 64 + nf * 16 + ln15] = acc[i][nf][j4];
      }
  }
}

// ---------------- windowed attention via MFMA (unchanged from round 11) ----------------
__global__ __launch_bounds__(256, 3) void attn_kernel(
    const u16t* __restrict__ qkT, const u16t* __restrict__ vbuf,
    const float* __restrict__ amask, u16t* __restrict__ attnT)
{
  __shared__ __align__(16) u16t sm[24576];   // 49152 B
  u16t* KP = sm;           // Kt rows stride 64, later P rows stride 192
  u16t* Vt = sm + 12288;   // rows stride 192

  const int t = threadIdx.x;
  const int lane = t & 63, w = t >> 6;
  const int fr = lane & 15, fc = lane >> 4;

  const int nid = (blockIdx.x & 7) * 96 + (blockIdx.x >> 3);
  const int h = nid / 64, qt = nid % 64;
  const int q0 = qt * 64;
  const int kstart = q0 - 64;

  if (q0 == 0) {
    *(uint4*)(KP + t * 8) = make_uint4(0, 0, 0, 0);
    *(uint4*)(KP + 2048 + t * 8) = make_uint4(0, 0, 0, 0);
#pragma unroll
    for (int j = 0; j < 2; ++j) {
      int unit = t + 256 * j;
      *(uint4*)(Vt + (unit >> 3) * 192 + (unit & 7) * 8) = make_uint4(0, 0, 0, 0);
    }
  } else if (q0 == S_LEN - 64) {
    *(uint4*)(KP + 8192 + t * 8) = make_uint4(0, 0, 0, 0);
    *(uint4*)(KP + 10240 + t * 8) = make_uint4(0, 0, 0, 0);
#pragma unroll
    for (int j = 0; j < 2; ++j) {
      int unit = t + 256 * j;
      *(uint4*)(Vt + (unit >> 3) * 192 + 128 + (unit & 7) * 8) = make_uint4(0, 0, 0, 0);
    }
  }

  const u16t* kcolbase = qkT + 768 + h * 64;
#pragma unroll
  for (int jj = 0; jj < 6; ++jj) {
    int ii = jj * 256 + t;
    int row = ii >> 3, ch = ii & 7;
    int key = kstart + row;
    if (key >= 0 && key < S_LEN)
      stage16(kcolbase + (size_t)key * 1536 + ((ch ^ (row & 7)) * 8),
              KP + (jj * 256 + w * 64) * 8);
  }
#pragma unroll
  for (int jj = 0; jj < 6; ++jj) {
    int ii = jj * 256 + t;
    int row = ii / 24, ch = ii - row * 24;
    int sc = (ch & 24) | ((ch & 7) ^ (row & 7));
    int kf = kstart + sc * 8;
    if (kf >= 0 && kf < S_LEN)
      stage16(vbuf + (size_t)(h * 64 + row) * S_LEN + kf,
              Vt + (jj * 256 + w * 64) * 8);
  }
  const u16t* qrow = qkT + (size_t)(q0 + w * 16 + fr) * 1536 + h * 64;
  bf16x8 qa0 = *(const bf16x8*)(qrow + fc * 8);
  bf16x8 qa1 = *(const bf16x8*)(qrow + 32 + fc * 8);

  // amask hoist: issue all 48 loads now; they complete by the barrier below
  float am[12][4];
  const int qb = q0 + w * 16 + fc * 4;
#pragma unroll
  for (int nt = 0; nt < 12; ++nt) {
    int key = kstart + nt * 16 + fr;
    int keyc = min(max(key, 0), S_LEN - 1);
#pragma unroll
    for (int r = 0; r < 4; ++r)
      am[nt][r] = amask[(size_t)(qb + r) * S_LEN + keyc];
  }

  __syncthreads();

  f32x4 acc[12];
#pragma unroll
  for (int nt = 0; nt < 12; ++nt) acc[nt] = (f32x4){0.f, 0.f, 0.f, 0.f};
  __builtin_amdgcn_s_setprio(1);
#pragma unroll
  for (int nt = 0; nt < 12; ++nt) {
    int row = nt * 16 + fr;
    bf16x8 kb0 = *(const bf16x8*)(KP + row * 64 + ((fc ^ (fr & 7)) * 8));
    acc[nt] = __builtin_amdgcn_mfma_f32_16x16x32_bf16(qa0, kb0, acc[nt], 0, 0, 0);
    bf16x8 kb1 = *(const bf16x8*)(KP + row * 64 + (((4 + fc) ^ (fr & 7)) * 8));
    acc[nt] = __builtin_amdgcn_mfma_f32_16x16x32_bf16(qa1, kb1, acc[nt], 0, 0, 0);
  }
  __builtin_amdgcn_s_setprio(0);

  float rm[4] = {-3.0e38f, -3.0e38f, -3.0e38f, -3.0e38f};
#pragma unroll
  for (int nt = 0; nt < 12; ++nt) {
    int kk = nt * 16 + fr;
    int key = kstart + kk;
#pragma unroll
    for (int r = 0; r < 4; ++r) {
      int q = w * 16 + fc * 4 + r;
      int dk = kk - q;
      bool inw = (key >= 0) && (key < S_LEN) && (dk >= 0) && (dk <= 128);
      float s = -3.0e38f;
      if (inw) s = acc[nt][r] * 0.125f + am[nt][r];
      acc[nt][r] = s;
      rm[r] = fmaxf(rm[r], s);
    }
  }
#pragma unroll
  for (int r = 0; r < 4; ++r)
#pragma unroll
    for (int off = 1; off < 16; off <<= 1)
      rm[r] = fmaxf(rm[r], __shfl_xor(rm[r], off));

  float rs[4] = {0.f, 0.f, 0.f, 0.f};
#pragma unroll
  for (int nt = 0; nt < 12; ++nt)
#pragma unroll
    for (int r = 0; r < 4; ++r) {
      float e = __expf(acc[nt][r] - rm[r]);
      acc[nt][r] = e;
      rs[r] += e;
    }
#pragma unroll
  for (int r = 0; r < 4; ++r)
#pragma unroll
    for (int off = 1; off < 16; off <<= 1)
      rs[r] += __shfl_xor(rs[r], off);

  __syncthreads();   // all waves done reading Kt -> safe to overwrite with P

#pragma unroll
  for (int nt = 0; nt < 12; ++nt) {
    int kk = nt * 16 + fr;
    int cg = kk >> 3;
#pragma unroll
    for (int r = 0; r < 4; ++r) {
      int q = w * 16 + fc * 4 + r;
      int csw = (cg & 24) | ((cg & 7) ^ (q & 7));
      KP[q * 192 + csw * 8 + (kk & 7)] = f2bf_u16(acc[nt][r]);
    }
  }
  // no barrier: PV reads only this wave's P rows; within-wave RAW is lgkm-ordered

  f32x4 acc2[4];
#pragma unroll
  for (int nt = 0; nt < 4; ++nt) acc2[nt] = (f32x4){0.f, 0.f, 0.f, 0.f};
  __builtin_amdgcn_s_setprio(1);
#pragma unroll
  for (int c32 = 0; c32 < 6; ++c32) {
    int cg = c32 * 4 + fc;
    int csA = (cg & 24) | ((cg & 7) ^ (fr & 7));
    bf16x8 pa = *(const bf16x8*)(KP + (w * 16 + fr) * 192 + csA * 8);
#pragma unroll
    for (int nt = 0; nt < 4; ++nt) {
      int d = nt * 16 + fr;
      bf16x8 vb = *(const bf16x8*)(Vt + d * 192 + csA * 8);
      acc2[nt] = __builtin_amdgcn_mfma_f32_16x16x32_bf16(pa, vb, acc2[nt], 0, 0, 0);
    }
  }
  __builtin_amdgcn_s_setprio(0);

  float inv[4];
#pragma unroll
  for (int r = 0; r < 4; ++r) inv[r] = 1.f / rs[r];
#pragma unroll
  for (int nt = 0; nt < 4; ++nt)
#pragma unroll
    for (int r = 0; r < 4; ++r) {
      int q = w * 16 + fc * 4 + r;
      int d = nt * 16 + fr;
      attnT[(size_t)(q0 + q) * 768 + h * 64 + d] = f2bf_u16(acc2[nt][r] * inv[r]);
    }
}

extern "C" void kernel_launch(void* const* d_in, const int* in_sizes, int n_in,
                              void* d_out, int out_size, void* d_ws, size_t ws_size,
                              hipStream_t stream) {
  const float* x     = (const float*)d_in[0];
  const int*   pos   = (const int*)d_in[1];
  const float* amask = (const float*)d_in[2];
  const float* qkvw  = (const float*)d_in[3];
  const float* outw  = (const float*)d_in[4];
  float* out = (float*)d_out;

  char* ws = (char*)d_ws;
  float* cosT   = (float*)ws;                          ws += 32 * S_LEN * 4;
  float* sinT   = (float*)ws;                          ws += 32 * S_LEN * 4;
  u16t*  xT     = (u16t*)ws;                           ws += (size_t)S_LEN * 768 * 2;
  u16t*  wq_bf  = (u16t*)ws;                           ws += (size_t)2304 * 768 * 2;
  u16t*  wo_bf  = (u16t*)ws;                           ws += (size_t)768 * 768 * 2;
  u16t*  qkT    = (u16t*)ws;                           ws += (size_t)S_LEN * 1536 * 2;
  u16t*  vbuf   = (u16t*)ws;                           ws += (size_t)768 * S_LEN * 2;
  u16t*  attnT  = (u16t*)ws;

  // fused prep: tcast(768) | castw wq(1728) | castw wo(576) | rope(512)
  prep_kernel<<<3584, 256, 0, stream>>>(x, xT, qkvw, wq_bf, outw, wo_bf, pos, cosT, sinT);
  // QKV: 18x32 tiles, XCD rect = 9m x 8n
  gemm_kernel<1><<<576, 256, 0, stream>>>(wq_bf, xT, qkT, vbuf, cosT, sinT, 1536, 32, 8, 9);
  attn_kernel<<<768, 256, 0, stream>>>(qkT, vbuf, amask, attnT);
  // out-proj: 6x32 tiles, XCD rect = 6m x 4n
  gemm_kernel<0><<<192, 256, 0, stream>>>(wo_bf, attnT, out, nullptr, cosT, sinT, 0, 32, 4, 6);
}

// Round 13
// 62.551 us; speedup vs baseline: 1.9680x; 1.0125x over previous
//
#include <hip/hip_runtime.h>
#include <hip/hip_bf16.h>
#include <math.h>

#define S_LEN 4096

typedef unsigned short u16t;
typedef unsigned int u32t;
typedef __attribute__((ext_vector_type(4))) short bf16x4;
typedef __attribute__((ext_vector_type(8))) short bf16x8;
typedef __attribute__((ext_vector_type(4))) float f32x4;

__device__ __forceinline__ u16t f2bf_u16(float f) {
  union { __hip_bfloat16 h; u16t u; } r; r.h = __float2bfloat16(f); return r.u;
}

// async global->LDS, 16B per lane; LDS dest = wave-uniform base + lane*16
__device__ __forceinline__ void stage16(const u16t* g, u16t* l) {
  __builtin_amdgcn_global_load_lds(
      (const __attribute__((address_space(1))) void*)g,
      (__attribute__((address_space(3))) void*)l, 16, 0, 0);
}

// ---------------- fused prep: tcast | castw(wq) | castw(wo) | rope ----------------
__global__ __launch_bounds__(256) void prep_kernel(
    const float* __restrict__ x, u16t* __restrict__ xT,
    const float* __restrict__ qkvw, u16t* __restrict__ wq,
    const float* __restrict__ outw, u16t* __restrict__ wo,
    const int* __restrict__ pos, float* __restrict__ cosT, float* __restrict__ sinT)
{
  __shared__ float T[64][65];
  const int b = blockIdx.x;
  const int t = threadIdx.x;
  if (b < 768) {
    int s0 = (b & 63) * 64, c0 = (b >> 6) * 64;
    int sl = t & 63, g = t >> 6;
#pragma unroll
    for (int r = 0; r < 16; ++r) {
      int cl = g + 4 * r;
      T[cl][sl] = x[(size_t)(c0 + cl) * S_LEN + s0 + sl];
    }
    __syncthreads();
#pragma unroll
    for (int r = 0; r < 16; ++r) {
      int sl2 = g + 4 * r;
      xT[(size_t)(s0 + sl2) * 768 + c0 + sl] = f2bf_u16(T[sl][sl2]);
    }
  } else if (b < 3072) {
    const float* src; u16t* dst; int i;
    if (b < 2496) { src = qkvw; dst = wq; i = (b - 768) * 256 + t; }
    else          { src = outw; dst = wo; i = (b - 2496) * 256 + t; }
    float4 v = ((const float4*)src)[i];
    union { u16t h[4]; uint2 u; } r;
    r.h[0] = f2bf_u16(v.x); r.h[1] = f2bf_u16(v.y);
    r.h[2] = f2bf_u16(v.z); r.h[3] = f2bf_u16(v.w);
    ((uint2*)dst)[i] = r.u;
  } else {
    // float trig: worst-case angle err ~4e-4 rad << bf16 quantization of q/k
    int idx = (b - 3072) * 256 + t;
    int j = idx >> 12, s = idx & 4095;
    float p = (float)pos[s];
    float inv = exp2f(-((float)(2 * j) / 64.0f) * 13.2877123795549f); // log2(1e4)
    float a = p * inv;
    cosT[idx] = cosf(a);
    sinT[idx] = sinf(a);
  }
}

// ---------------- bf16 MFMA GEMM, 128x128 tile, BK=32, dual-tile phases ----
// (frozen from round 12; see comments there. sched_barrier(0) pins REQUIRED.)
template <int MODE>
__global__ __launch_bounds__(256, 3) void gemm_kernel(
    const u16t* __restrict__ A, const u16t* __restrict__ Bt,
    void* __restrict__ C1, void* __restrict__ C2,
    const float* __restrict__ cosT, const float* __restrict__ sinT, int ropeRows,
    int tilesX, int rectW, int rectH)
{
  __shared__ __align__(16) u16t smem[24576];   // 3 x 16KB buffers; epilogue reuses
  const int t = threadIdx.x;
  const int lane = t & 63, w = t >> 6;
  const int wr = w >> 1, wc = w & 1;
  const int ln15 = lane & 15, ln4 = lane >> 4;

  const int xcd = blockIdx.x & 7;
  const int local = blockIdx.x >> 3;
  const int nrectX = tilesX / rectW;
  const int lm = local / rectW, ln = local - lm * rectW;
  const int m0 = ((xcd / nrectX) * rectH + lm) * 128;
  const int n0 = ((xcd % nrectX) * rectW + ln) * 128;

  f32x4 acc[4][4];
#pragma unroll
  for (int i = 0; i < 4; ++i)
#pragma unroll
    for (int j = 0; j < 4; ++j) acc[i][j] = (f32x4){0.f, 0.f, 0.f, 0.f};

  const int srow = w * 32 + (lane >> 2);
  const int sch  = ((lane & 3) ^ ((lane >> 3) & 3)) * 8;
  const u16t* gA0 = A  + (size_t)(m0 + srow) * 768 + sch;
  const u16t* gB0 = Bt + (size_t)(n0 + srow) * 768 + sch;
  const u16t* gA1 = gA0 + 16 * 768;
  const u16t* gB1 = gB0 + 16 * 768;
  const int dA = w * 1024;
  const int dB = 4096 + w * 1024;

#pragma unroll
  for (int p = 0; p < 3; ++p) {
    u16t* b = smem + p * 8192;
    stage16(gA0 + p * 32, b + dA);
    stage16(gA1 + p * 32, b + dA + 512);
    stage16(gB0 + p * 32, b + dB);
    stage16(gB1 + p * 32, b + dB + 512);
  }

  const int sg = (ln4 ^ ((ln15 >> 1) & 3)) * 8;

#pragma unroll
  for (int ph = 0; ph < 12; ++ph) {
    const int b0 = (2 * ph) % 3;
    const int b1 = (2 * ph + 1) % 3;
    u16t* c0 = smem + b0 * 8192;
    u16t* c1 = smem + b1 * 8192;
    if (ph < 11) asm volatile("s_waitcnt vmcnt(4)" ::: "memory");
    else         asm volatile("s_waitcnt vmcnt(0)" ::: "memory");
    __builtin_amdgcn_s_barrier();
    __builtin_amdgcn_sched_barrier(0);   // ds_reads must not hoist above barrier
    {
      bf16x8 af[4], bg[4];
#pragma unroll
      for (int f = 0; f < 4; ++f) {
        af[f] = *(const bf16x8*)(c0 + (wr * 64 + f * 16 + ln15) * 32 + sg);
        bg[f] = *(const bf16x8*)(c0 + 4096 + (wc * 64 + f * 16 + ln15) * 32 + sg);
      }
#pragma unroll
      for (int i = 0; i < 4; ++i)
#pragma unroll
        for (int j = 0; j < 4; ++j)
          acc[i][j] = __builtin_amdgcn_mfma_f32_16x16x32_bf16(af[i], bg[j], acc[i][j], 0, 0, 0);
#pragma unroll
      for (int f = 0; f < 4; ++f) {
        af[f] = *(const bf16x8*)(c1 + (wr * 64 + f * 16 + ln15) * 32 + sg);
        bg[f] = *(const bf16x8*)(c1 + 4096 + (wc * 64 + f * 16 + ln15) * 32 + sg);
      }
#pragma unroll
      for (int i = 0; i < 4; ++i)
#pragma unroll
        for (int j = 0; j < 4; ++j)
          acc[i][j] = __builtin_amdgcn_mfma_f32_16x16x32_bf16(af[i], bg[j], acc[i][j], 0, 0, 0);
    }
    __builtin_amdgcn_sched_barrier(0);   // reads complete before the barrier
    __builtin_amdgcn_s_barrier();        // all waves done reading c0/c1
    __builtin_amdgcn_sched_barrier(0);   // refill must not hoist above barrier
    if (ph <= 9) {
      const int ko3 = (2 * ph + 3) * 32;   // -> buf b0 (needed next phase: first)
      const int ko4 = (2 * ph + 4) * 32;   // -> buf b1
      stage16(gA0 + ko3, c0 + dA);
      stage16(gA1 + ko3, c0 + dA + 512);
      stage16(gB0 + ko3, c0 + dB);
      stage16(gB1 + ko3, c0 + dB + 512);
      stage16(gA0 + ko4, c1 + dA);
      stage16(gA1 + ko4, c1 + dA + 512);
      stage16(gB0 + ko4, c1 + dB);
      stage16(gB1 + ko4, c1 + dB + 512);
    } else if (ph == 10) {
      const int ko3 = 23 * 32;             // tile 23 -> buf b0 (23%3 == b0)
      stage16(gA0 + ko3, c0 + dA);
      stage16(gA1 + ko3, c0 + dA + 512);
      stage16(gB0 + ko3, c0 + dB);
      stage16(gB1 + ko3, c0 + dB + 512);
    }
  }

  const int mq = m0 + wr * 64;
  if (mq < ropeRows) {
#pragma unroll
    for (int j4 = 0; j4 < 4; ++j4)
#pragma unroll
      for (int nf = 0; nf < 4; ++nf) {
        int n = n0 + wc * 64 + nf * 16 + ln15;
#pragma unroll
        for (int p = 0; p < 2; ++p) {
          int fidx = p * 16 + ln4 * 4 + j4;
          float cc = cosT[fidx * S_LEN + n], ss = sinT[fidx * S_LEN + n];
          float lo = acc[p][nf][j4], hi = acc[p + 2][nf][j4];
          acc[p][nf][j4]     = lo * cc - hi * ss;
          acc[p + 2][nf][j4] = hi * cc + lo * ss;
        }
      }
  }

  if (MODE == 1 && m0 < 1536) {
    __syncthreads();
    u16t* Cs = smem;
#pragma unroll
    for (int i = 0; i < 4; ++i)
#pragma unroll
      for (int nf = 0; nf < 4; ++nf) {
        int n_l = wc * 64 + nf * 16 + ln15;
        int m_l = wr * 64 + i * 16 + ln4 * 4;
        union { u16t h[4]; uint2 u2; } pk;
#pragma unroll
        for (int j4 = 0; j4 < 4; ++j4) pk.h[j4] = f2bf_u16(acc[i][nf][j4]);
        *(uint2*)(Cs + n_l * 136 + m_l) = pk.u2;
      }
    __syncthreads();
    u16t* Co = (u16t*)C1;   // qkT [4096][1536]
#pragma unroll
    for (int it = 0; it < 8; ++it) {
      int idx = it * 256 + t;
      int row = idx >> 4, ch = idx & 15;
      *(uint4*)&Co[(size_t)(n0 + row) * 1536 + m0 + ch * 8] =
          *(const uint4*)&Cs[row * 136 + ch * 8];
    }
  } else if (MODE == 1) {
    __syncthreads();
    u16t* Cs = smem;
#pragma unroll
    for (int i = 0; i < 4; ++i)
#pragma unroll
      for (int j4 = 0; j4 < 4; ++j4) {
        int mrow = wr * 64 + i * 16 + ln4 * 4 + j4;
#pragma unroll
        for (int nf = 0; nf < 4; ++nf) {
          int col = wc * 64 + nf * 16 + ln15;
          Cs[mrow * 128 + col] = f2bf_u16(acc[i][nf][j4]);
        }
      }
    __syncthreads();
    u16t* Co = (u16t*)C2;
#pragma unroll
    for (int it = 0; it < 8; ++it) {
      int idx = it * 256 + t;
      int row = idx >> 4, ch = idx & 15;
      *(uint4*)&Co[(size_t)(m0 - 1536 + row) * S_LEN + n0 + ch * 8] =
          *(const uint4*)&Cs[row * 128 + ch * 8];
    }
  } else {
    float* Co = (float*)C1;
#pragma unroll
    for (int i = 0; i < 4; ++i)
#pragma unroll
      for (int j4 = 0; j4 < 4; ++j4) {
        int m = m0 + wr * 64 + i * 16 + ln4 * 4 + j4;
#pragma unroll
        for (int nf = 0; nf < 4; ++nf)
          Co[(size_t)m * S_LEN + n0 + wc * 64 + nf * 16 + ln15] = acc[i][nf][j4];
      }
  }
}

// ---------------- windowed attention via MFMA ----------------
// round-12 structure; amask loads PREDICATED (exec-masked) instead of clamped:
// out-of-window lanes issue no fetch -> ~33% of amask bytes saved (attn is
// byte-bound, so bytes convert to time).
__global__ __launch_bounds__(256, 3) void attn_kernel(
    const u16t* __restrict__ qkT, const u16t* __restrict__ vbuf,
    const float* __restrict__ amask, u16t* __restrict__ attnT)
{
  __shared__ __align__(16) u16t sm[24576];   // 49152 B
  u16t* KP = sm;           // Kt rows stride 64, later P rows stride 192
  u16t* Vt = sm + 12288;   // rows stride 192

  const int t = threadIdx.x;
  const int lane = t & 63, w = t >> 6;
  const int fr = lane & 15, fc = lane >> 4;

  const int nid = (blockIdx.x & 7) * 96 + (blockIdx.x >> 3);
  const int h = nid / 64, qt = nid % 64;
  const int q0 = qt * 64;
  const int kstart = q0 - 64;

  if (q0 == 0) {
    *(uint4*)(KP + t * 8) = make_uint4(0, 0, 0, 0);
    *(uint4*)(KP + 2048 + t * 8) = make_uint4(0, 0, 0, 0);
#pragma unroll
    for (int j = 0; j < 2; ++j) {
      int unit = t + 256 * j;
      *(uint4*)(Vt + (unit >> 3) * 192 + (unit & 7) * 8) = make_uint4(0, 0, 0, 0);
    }
  } else if (q0 == S_LEN - 64) {
    *(uint4*)(KP + 8192 + t * 8) = make_uint4(0, 0, 0, 0);
    *(uint4*)(KP + 10240 + t * 8) = make_uint4(0, 0, 0, 0);
#pragma unroll
    for (int j = 0; j < 2; ++j) {
      int unit = t + 256 * j;
      *(uint4*)(Vt + (unit >> 3) * 192 + 128 + (unit & 7) * 8) = make_uint4(0, 0, 0, 0);
    }
  }

  const u16t* kcolbase = qkT + 768 + h * 64;
#pragma unroll
  for (int jj = 0; jj < 6; ++jj) {
    int ii = jj * 256 + t;
    int row = ii >> 3, ch = ii & 7;
    int key = kstart + row;
    if (key >= 0 && key < S_LEN)
      stage16(kcolbase + (size_t)key * 1536 + ((ch ^ (row & 7)) * 8),
              KP + (jj * 256 + w * 64) * 8);
  }
#pragma unroll
  for (int jj = 0; jj < 6; ++jj) {
    int ii = jj * 256 + t;
    int row = ii / 24, ch = ii - row * 24;
    int sc = (ch & 24) | ((ch & 7) ^ (row & 7));
    int kf = kstart + sc * 8;
    if (kf >= 0 && kf < S_LEN)
      stage16(vbuf + (size_t)(h * 64 + row) * S_LEN + kf,
              Vt + (jj * 256 + w * 64) * 8);
  }
  const u16t* qrow = qkT + (size_t)(q0 + w * 16 + fr) * 1536 + h * 64;
  bf16x8 qa0 = *(const bf16x8*)(qrow + fc * 8);
  bf16x8 qa1 = *(const bf16x8*)(qrow + 32 + fc * 8);

  // amask: predicated issue-early loads (only in-window lanes fetch)
  float am[12][4];
  const int qb = q0 + w * 16 + fc * 4;
#pragma unroll
  for (int nt = 0; nt < 12; ++nt) {
    int kk = nt * 16 + fr;
    int key = kstart + kk;
#pragma unroll
    for (int r = 0; r < 4; ++r) {
      int q = w * 16 + fc * 4 + r;
      int dk = kk - q;
      bool inw = (key >= 0) && (key < S_LEN) && (dk >= 0) && (dk <= 128);
      am[nt][r] = inw ? amask[(size_t)(qb + r) * S_LEN + key] : 0.f;
    }
  }

  __syncthreads();

  f32x4 acc[12];
#pragma unroll
  for (int nt = 0; nt < 12; ++nt) acc[nt] = (f32x4){0.f, 0.f, 0.f, 0.f};
  __builtin_amdgcn_s_setprio(1);
#pragma unroll
  for (int nt = 0; nt < 12; ++nt) {
    int row = nt * 16 + fr;
    bf16x8 kb0 = *(const bf16x8*)(KP + row * 64 + ((fc ^ (fr & 7)) * 8));
    acc[nt] = __builtin_amdgcn_mfma_f32_16x16x32_bf16(qa0, kb0, acc[nt], 0, 0, 0);
    bf16x8 kb1 = *(const bf16x8*)(KP + row * 64 + (((4 + fc) ^ (fr & 7)) * 8));
    acc[nt] = __builtin_amdgcn_mfma_f32_16x16x32_bf16(qa1, kb1, acc[nt], 0, 0, 0);
  }
  __builtin_amdgcn_s_setprio(0);

  float rm[4] = {-3.0e38f, -3.0e38f, -3.0e38f, -3.0e38f};
#pragma unroll
  for (int nt = 0; nt < 12; ++nt) {
    int kk = nt * 16 + fr;
    int key = kstart + kk;
#pragma unroll
    for (int r = 0; r < 4; ++r) {
      int q = w * 16 + fc * 4 + r;
      int dk = kk - q;
      bool inw = (key >= 0) && (key < S_LEN) && (dk >= 0) && (dk <= 128);
      float s = -3.0e38f;
      if (inw) s = acc[nt][r] * 0.125f + am[nt][r];
      acc[nt][r] = s;
      rm[r] = fmaxf(rm[r], s);
    }
  }
#pragma unroll
  for (int r = 0; r < 4; ++r)
#pragma unroll
    for (int off = 1; off < 16; off <<= 1)
      rm[r] = fmaxf(rm[r], __shfl_xor(rm[r], off));

  float rs[4] = {0.f, 0.f, 0.f, 0.f};
#pragma unroll
  for (int nt = 0; nt < 12; ++nt)
#pragma unroll
    for (int r = 0; r < 4; ++r) {
      float e = __expf(acc[nt][r] - rm[r]);
      acc[nt][r] = e;
      rs[r] += e;
    }
#pragma unroll
  for (int r = 0; r < 4; ++r)
#pragma unroll
    for (int off = 1; off < 16; off <<= 1)
      rs[r] += __shfl_xor(rs[r], off);

  __syncthreads();   // all waves done reading Kt -> safe to overwrite with P

#pragma unroll
  for (int nt = 0; nt < 12; ++nt) {
    int kk = nt * 16 + fr;
    int cg = kk >> 3;
#pragma unroll
    for (int r = 0; r < 4; ++r) {
      int q = w * 16 + fc * 4 + r;
      int csw = (cg & 24) | ((cg & 7) ^ (q & 7));
      KP[q * 192 + csw * 8 + (kk & 7)] = f2bf_u16(acc[nt][r]);
    }
  }
  // no barrier: PV reads only this wave's P rows; within-wave RAW is lgkm-ordered

  f32x4 acc2[4];
#pragma unroll
  for (int nt = 0; nt < 4; ++nt) acc2[nt] = (f32x4){0.f, 0.f, 0.f, 0.f};
  __builtin_amdgcn_s_setprio(1);
#pragma unroll
  for (int c32 = 0; c32 < 6; ++c32) {
    int cg = c32 * 4 + fc;
    int csA = (cg & 24) | ((cg & 7) ^ (fr & 7));
    bf16x8 pa = *(const bf16x8*)(KP + (w * 16 + fr) * 192 + csA * 8);
#pragma unroll
    for (int nt = 0; nt < 4; ++nt) {
      int d = nt * 16 + fr;
      bf16x8 vb = *(const bf16x8*)(Vt + d * 192 + csA * 8);
      acc2[nt] = __builtin_amdgcn_mfma_f32_16x16x32_bf16(pa, vb, acc2[nt], 0, 0, 0);
    }
  }
  __builtin_amdgcn_s_setprio(0);

  float inv[4];
#pragma unroll
  for (int r = 0; r < 4; ++r) inv[r] = 1.f / rs[r];
#pragma unroll
  for (int nt = 0; nt < 4; ++nt)
#pragma unroll
    for (int r = 0; r < 4; ++r) {
      int q = w * 16 + fc * 4 + r;
      int d = nt * 16 + fr;
      attnT[(size_t)(q0 + q) * 768 + h * 64 + d] = f2bf_u16(acc2[nt][r] * inv[r]);
    }
}

extern "C" void kernel_launch(void* const* d_in, const int* in_sizes, int n_in,
                              void* d_out, int out_size, void* d_ws, size_t ws_size,
                              hipStream_t stream) {
  const float* x     = (const float*)d_in[0];
  const int*   pos   = (const int*)d_in[1];
  const float* amask = (const float*)d_in[2];
  const float* qkvw  = (const float*)d_in[3];
  const float* outw  = (const float*)d_in[4];
  float* out = (float*)d_out;

  char* ws = (char*)d_ws;
  float* cosT   = (float*)ws;                          ws += 32 * S_LEN * 4;
  float* sinT   = (float*)ws;                          ws += 32 * S_LEN * 4;
  u16t*  xT     = (u16t*)ws;                           ws += (size_t)S_LEN * 768 * 2;
  u16t*  wq_bf  = (u16t*)ws;                           ws += (size_t)2304 * 768 * 2;
  u16t*  wo_bf  = (u16t*)ws;                           ws += (size_t)768 * 768 * 2;
  u16t*  qkT    = (u16t*)ws;                           ws += (size_t)S_LEN * 1536 * 2;
  u16t*  vbuf   = (u16t*)ws;                           ws += (size_t)768 * S_LEN * 2;
  u16t*  attnT  = (u16t*)ws;

  // fused prep: tcast(768) | castw wq(1728) | castw wo(576) | rope(512)
  prep_kernel<<<3584, 256, 0, stream>>>(x, xT, qkvw, wq_bf, outw, wo_bf, pos, cosT, sinT);
  // QKV: 18x32 tiles, XCD rect = 9m x 8n
  gemm_kernel<1><<<576, 256, 0, stream>>>(wq_bf, xT, qkT, vbuf, cosT, sinT, 1536, 32, 8, 9);
  attn_kernel<<<768, 256, 0, stream>>>(qkT, vbuf, amask, attnT);
  // out-proj: 6x32 tiles, XCD rect = 6m x 4n
  gemm_kernel<0><<<192, 256, 0, stream>>>(wo_bf, attnT, out, nullptr, cosT, sinT, 0, 32, 4, 6);
}